// Round 3
// baseline (3710.988 us; speedup 1.0000x reference)
//
#include <hip/hip_runtime.h>
#include <math.h>

#define B_ 256
#define L_ 49
#define V_ 10000
#define E_ 512
#define H_ 512
#define K_ 512
#define T_ 15

// ---------------------------------------------------------------------------
// Generic fp32 GEMM: C[M,N] = A[M,Kd] @ Bw[N,Kd]^T + bias[N]
// 64x64 tile, Kstep=16, 256 threads, 4x4 per thread. Kd must be %16.
// ---------------------------------------------------------------------------
__global__ __launch_bounds__(256) void gemm_nt_kernel(
    const float* __restrict__ A, const float* __restrict__ Bw,
    const float* __restrict__ bias, float* __restrict__ C,
    int M, int N, int Kd, int ldc)
{
    __shared__ float As[16][64];
    __shared__ float Bs[16][64];
    const int tid = threadIdx.x;
    const int tx = tid & 15, ty = tid >> 4;
    const int row0 = blockIdx.y * 64;
    const int col0 = blockIdx.x * 64;
    const int lr = tid >> 2;          // 0..63 row-within-tile for staging
    const int lk = (tid & 3) << 2;    // 0,4,8,12 k-offset for staging
    float acc[4][4] = {};

    for (int k0 = 0; k0 < Kd; k0 += 16) {
        float4 av = make_float4(0.f, 0.f, 0.f, 0.f);
        float4 bv = make_float4(0.f, 0.f, 0.f, 0.f);
        const int ar = row0 + lr;
        const int br = col0 + lr;
        if (ar < M) av = *reinterpret_cast<const float4*>(&A[(size_t)ar * Kd + k0 + lk]);
        if (br < N) bv = *reinterpret_cast<const float4*>(&Bw[(size_t)br * Kd + k0 + lk]);
        As[lk + 0][lr] = av.x; As[lk + 1][lr] = av.y;
        As[lk + 2][lr] = av.z; As[lk + 3][lr] = av.w;
        Bs[lk + 0][lr] = bv.x; Bs[lk + 1][lr] = bv.y;
        Bs[lk + 2][lr] = bv.z; Bs[lk + 3][lr] = bv.w;
        __syncthreads();
#pragma unroll
        for (int kk = 0; kk < 16; ++kk) {
            const float4 a = *reinterpret_cast<const float4*>(&As[kk][ty << 2]);
            const float4 b = *reinterpret_cast<const float4*>(&Bs[kk][tx << 2]);
            const float ar4[4] = {a.x, a.y, a.z, a.w};
            const float br4[4] = {b.x, b.y, b.z, b.w};
#pragma unroll
            for (int i = 0; i < 4; ++i)
#pragma unroll
                for (int j = 0; j < 4; ++j)
                    acc[i][j] = fmaf(ar4[i], br4[j], acc[i][j]);
        }
        __syncthreads();
    }

#pragma unroll
    for (int i = 0; i < 4; ++i) {
        const int row = row0 + (ty << 2) + i;
        if (row >= M) continue;
#pragma unroll
        for (int j = 0; j < 4; ++j) {
            const int col = col0 + (tx << 2) + j;
            if (col < N) C[(size_t)row * ldc + col] = acc[i][j] + bias[col];
        }
    }
}

// ---------------------------------------------------------------------------
// Additive attention per batch row b:
//   s[l]  = sum_h tanh(q[b,h] + kp[b,l,h]) * Va[h] + bva
//   w     = softmax(s over L)
//   ctx[b,k] = sum_l w[l] * feat[b,l,k]
// One block per b. 256 threads = 4 waves. Each wave owns l = wave,wave+4,...
// ---------------------------------------------------------------------------
__global__ __launch_bounds__(256) void attn_kernel(
    const float* __restrict__ q, const float* __restrict__ kp,
    const float* __restrict__ feat, const float* __restrict__ Va,
    const float* __restrict__ bva, float* __restrict__ ctx)
{
    const int b = blockIdx.x;
    const int tid = threadIdx.x;
    const int lane = tid & 63;
    const int wave = tid >> 6;
    __shared__ float s_sc[64];
    __shared__ float s_w[64];

    float qr[8], va[8];
    const float* qb = q + (size_t)b * H_;
#pragma unroll
    for (int i = 0; i < 8; ++i) {
        qr[i] = qb[lane * 8 + i];
        va[i] = Va[lane * 8 + i];
    }

    for (int l = wave; l < L_; l += 4) {
        const float* kpl = kp + ((size_t)b * L_ + l) * H_ + lane * 8;
        float s = 0.f;
#pragma unroll
        for (int i = 0; i < 8; ++i) s += tanhf(qr[i] + kpl[i]) * va[i];
#pragma unroll
        for (int off = 32; off > 0; off >>= 1) s += __shfl_xor(s, off, 64);
        if (lane == 0) s_sc[l] = s + bva[0];
    }
    __syncthreads();

    if (wave == 0) {
        const float v = (lane < L_) ? s_sc[lane] : -1e30f;
        float m = v;
#pragma unroll
        for (int off = 32; off > 0; off >>= 1) m = fmaxf(m, __shfl_xor(m, off, 64));
        const float e = (lane < L_) ? expf(v - m) : 0.f;
        float ssum = e;
#pragma unroll
        for (int off = 32; off > 0; off >>= 1) ssum += __shfl_xor(ssum, off, 64);
        if (lane < L_) s_w[lane] = e / ssum;
    }
    __syncthreads();

#pragma unroll
    for (int r = 0; r < K_ / 256; ++r) {
        const int k = tid + r * 256;
        float acc = 0.f;
        const float* fb = feat + (size_t)b * L_ * K_ + k;
        for (int l = 0; l < L_; ++l) acc += s_w[l] * fb[(size_t)l * K_];
        ctx[(size_t)b * K_ + k] = acc;
    }
}

// ---------------------------------------------------------------------------
// x[b] = concat(emb[captions[b,t]], ctx2[b])    -> [B, E_+H_]
// ---------------------------------------------------------------------------
__global__ __launch_bounds__(256) void concat_kernel(
    const int* __restrict__ captions, int t,
    const float* __restrict__ emb, const float* __restrict__ ctx2,
    float* __restrict__ x)
{
    const int b = blockIdx.x;
    const int tid = threadIdx.x;
    const int cap = captions[(size_t)b * T_ + t];
    const int off = tid * 4;   // 0..1020
    float4 v;
    if (off < E_) v = *reinterpret_cast<const float4*>(&emb[(size_t)cap * E_ + off]);
    else          v = *reinterpret_cast<const float4*>(&ctx2[(size_t)b * H_ + (off - E_)]);
    *reinterpret_cast<float4*>(&x[(size_t)b * (E_ + H_) + off]) = v;
}

// ---------------------------------------------------------------------------
// GRU gate fusion, in-place h update.
// ---------------------------------------------------------------------------
__global__ __launch_bounds__(256) void gru_kernel(
    const float* __restrict__ gi, const float* __restrict__ gh,
    float* __restrict__ h)
{
    const int idx = blockIdx.x * 256 + threadIdx.x;   // < B_*H_
    const int b = idx >> 9;
    const int j = idx & (H_ - 1);
    const size_t o = (size_t)b * 3 * H_ + j;
    const float ir = gi[o],        hr = gh[o];
    const float iz = gi[o + H_],   hz = gh[o + H_];
    const float in_ = gi[o + 2 * H_], hn = gh[o + 2 * H_];
    const float r = 1.f / (1.f + expf(-(ir + hr)));
    const float z = 1.f / (1.f + expf(-(iz + hz)));
    const float n = tanhf(in_ + r * hn);
    h[idx] = (1.f - z) * n + z * h[idx];
}

// ---------------------------------------------------------------------------
extern "C" void kernel_launch(void* const* d_in, const int* in_sizes, int n_in,
                              void* d_out, int out_size, void* d_ws, size_t ws_size,
                              hipStream_t stream)
{
    const float* features = (const float*)d_in[0];
    const int*   captions = (const int*)d_in[1];
    const float* emb  = (const float*)d_in[2];
    const float* Wq   = (const float*)d_in[3];
    const float* bq   = (const float*)d_in[4];
    const float* Uk   = (const float*)d_in[5];
    const float* bk   = (const float*)d_in[6];
    const float* Va   = (const float*)d_in[7];
    const float* bva  = (const float*)d_in[8];
    const float* W0   = (const float*)d_in[9];
    const float* b0   = (const float*)d_in[10];
    const float* Wih  = (const float*)d_in[11];
    const float* bih  = (const float*)d_in[12];
    const float* Whh  = (const float*)d_in[13];
    const float* bhh  = (const float*)d_in[14];
    const float* W1   = (const float*)d_in[15];
    const float* b1   = (const float*)d_in[16];
    float* out = (float*)d_out;

    float* ws = (float*)d_ws;
    float* kp   = ws; ws += (size_t)B_ * L_ * H_;   // 6.42M
    float* h    = ws; ws += B_ * H_;
    float* q    = ws; ws += B_ * H_;
    float* ctx  = ws; ws += B_ * K_;
    float* ctx2 = ws; ws += B_ * H_;
    float* x    = ws; ws += B_ * (E_ + H_);
    float* gi   = ws; ws += B_ * 3 * H_;
    float* gh   = ws; ws += B_ * 3 * H_;

    hipMemsetAsync(h, 0, (size_t)B_ * H_ * sizeof(float), stream);

    const dim3 blk(256);

    // keys_proj = features @ Uk^T + bk   [B*L, H]
    gemm_nt_kernel<<<dim3(H_ / 64, (B_ * L_) / 64), blk, 0, stream>>>(
        features, Uk, bk, kp, B_ * L_, H_, K_, H_);

    for (int t = 0; t < T_; ++t) {
        // q = h @ Wq^T + bq
        gemm_nt_kernel<<<dim3(H_ / 64, B_ / 64), blk, 0, stream>>>(
            h, Wq, bq, q, B_, H_, H_, H_);
        // attention -> ctx
        attn_kernel<<<dim3(B_), blk, 0, stream>>>(q, kp, features, Va, bva, ctx);
        // ctx2 = ctx @ W0^T + b0
        gemm_nt_kernel<<<dim3(H_ / 64, B_ / 64), blk, 0, stream>>>(
            ctx, W0, b0, ctx2, B_, H_, K_, H_);
        // x = [emb_t, ctx2]
        concat_kernel<<<dim3(B_), blk, 0, stream>>>(captions, t, emb, ctx2, x);
        // gi = x @ Wih^T + bih
        gemm_nt_kernel<<<dim3(3 * H_ / 64, B_ / 64), blk, 0, stream>>>(
            x, Wih, bih, gi, B_, 3 * H_, E_ + H_, 3 * H_);
        // gh = h @ Whh^T + bhh
        gemm_nt_kernel<<<dim3(3 * H_ / 64, B_ / 64), blk, 0, stream>>>(
            h, Whh, bhh, gh, B_, 3 * H_, H_, 3 * H_);
        // GRU update (in-place h)
        gru_kernel<<<dim3(B_ * H_ / 256), blk, 0, stream>>>(gi, gh, h);
        // out_t = h @ W1^T + b1  -> d_out[:, t, :]
        gemm_nt_kernel<<<dim3((V_ + 63) / 64, B_ / 64), blk, 0, stream>>>(
            h, W1, b1, out + (size_t)t * V_, B_, V_, H_, T_ * V_);
    }
}

// Round 4
// 3008.280 us; speedup vs baseline: 1.2336x; 1.2336x over previous
//
#include <hip/hip_runtime.h>
#include <hip/hip_bf16.h>
#include <math.h>

#define B_ 256
#define L_ 49
#define V_ 10000
#define E_ 512
#define H_ 512
#define K_ 512
#define T_ 15

typedef __bf16 bf16x8 __attribute__((ext_vector_type(8)));
typedef float f32x4 __attribute__((ext_vector_type(4)));

#define AS1 __attribute__((address_space(1)))
#define AS3 __attribute__((address_space(3)))

// ---------------------------------------------------------------------------
// One-time fp32 -> bf16 cast (RNE via __hip_bfloat16 ctor), 4 elems/thread.
// ---------------------------------------------------------------------------
__global__ __launch_bounds__(256) void cvt_f32_bf16_kernel(
    const float* __restrict__ in, __hip_bfloat16* __restrict__ out, int n4)
{
    const int i = blockIdx.x * 256 + threadIdx.x;
    if (i >= n4) return;
    const float4 v = ((const float4*)in)[i];
    __hip_bfloat16 o[4];
    o[0] = (__hip_bfloat16)v.x; o[1] = (__hip_bfloat16)v.y;
    o[2] = (__hip_bfloat16)v.z; o[3] = (__hip_bfloat16)v.w;
    *(ushort4*)(out + (size_t)i * 4) = *(ushort4*)o;
}

// ---------------------------------------------------------------------------
// bf16 MFMA GEMM (NT): C[M,N] = A[M,Kd] @ Bw[N,Kd]^T + bias[N], C fp32.
// 64x64 tile, BK=64, 256 thr = 4 waves (2x2), each wave 32x32 via 2x2
// mfma_f32_16x16x32_bf16 frags. global_load_lds(16B) staging, linear LDS
// (m97 2-barrier structure). M%64==0 and Kd%64==0 required; N tail guarded.
// ---------------------------------------------------------------------------
__global__ __launch_bounds__(256) void gemm_bf16_nt_kernel(
    const __hip_bfloat16* __restrict__ A, const __hip_bfloat16* __restrict__ Bw,
    const float* __restrict__ bias, float* __restrict__ C,
    int M, int N, int Kd, int ldc)
{
    __shared__ __hip_bfloat16 Asl[64 * 64];
    __shared__ __hip_bfloat16 Bsl[64 * 64];
    const int tid  = threadIdx.x;
    const int lane = tid & 63;
    const int w    = tid >> 6;
    const int wm   = w >> 1, wn = w & 1;
    const int row0 = blockIdx.y * 64;
    const int col0 = blockIdx.x * 64;

    // staging map: thread t loads 8 bf16 (16B) at tile row (t>>3), elem (t&7)*8
    const int srow = tid >> 3;          // 0..31 (+32 on 2nd issue)
    const int scol = (tid & 7) << 3;    // 0..56

    // fragment map (16x16x32): lane holds row/col = lane&15, k = (lane>>4)*8 + j
    const int lr = lane & 15;
    const int lk = (lane >> 4) << 3;

    f32x4 acc[2][2] = {};

    const __hip_bfloat16* gA0 = A + (size_t)(row0 + srow) * Kd + scol;
    const __hip_bfloat16* gA1 = gA0 + (size_t)32 * Kd;
    const int br0 = col0 + srow, br1 = br0 + 32;
    const __hip_bfloat16* gB0 = Bw + (size_t)br0 * Kd + scol;
    const __hip_bfloat16* gB1 = gB0 + (size_t)32 * Kd;
    const bool v0 = br0 < N, v1 = br1 < N;

    for (int k0 = 0; k0 < Kd; k0 += 64) {
        __syncthreads();   // prior iteration's ds_reads done before overwrite
        __builtin_amdgcn_global_load_lds((const AS1 void*)(gA0 + k0),
            (AS3 void*)(Asl + tid * 8), 16, 0, 0);
        __builtin_amdgcn_global_load_lds((const AS1 void*)(gA1 + k0),
            (AS3 void*)(Asl + 2048 + tid * 8), 16, 0, 0);
        if (v0) __builtin_amdgcn_global_load_lds((const AS1 void*)(gB0 + k0),
            (AS3 void*)(Bsl + tid * 8), 16, 0, 0);
        if (v1) __builtin_amdgcn_global_load_lds((const AS1 void*)(gB1 + k0),
            (AS3 void*)(Bsl + 2048 + tid * 8), 16, 0, 0);
        __syncthreads();   // compiler emits s_waitcnt vmcnt(0) before barrier

#pragma unroll
        for (int ks = 0; ks < 2; ++ks) {
            bf16x8 af[2], bfr[2];
#pragma unroll
            for (int i = 0; i < 2; ++i)
                af[i] = *(const bf16x8*)(Asl + (wm * 32 + i * 16 + lr) * 64 + ks * 32 + lk);
#pragma unroll
            for (int j = 0; j < 2; ++j)
                bfr[j] = *(const bf16x8*)(Bsl + (wn * 32 + j * 16 + lr) * 64 + ks * 32 + lk);
#pragma unroll
            for (int i = 0; i < 2; ++i)
#pragma unroll
                for (int j = 0; j < 2; ++j)
                    acc[i][j] = __builtin_amdgcn_mfma_f32_16x16x32_bf16(
                        af[i], bfr[j], acc[i][j], 0, 0, 0);
        }
    }

    // C/D layout: col = lane&15, row = (lane>>4)*4 + reg  [m89-verified]
    const int orow = (lane >> 4) << 2;
#pragma unroll
    for (int i = 0; i < 2; ++i) {
#pragma unroll
        for (int j = 0; j < 2; ++j) {
            const int col = col0 + wn * 32 + j * 16 + lr;
            if (col >= N) continue;
            const float bv = bias[col];
            const int rowb = row0 + wm * 32 + i * 16 + orow;
#pragma unroll
            for (int r = 0; r < 4; ++r)
                C[(size_t)(rowb + r) * ldc + col] = acc[i][j][r] + bv;
        }
    }
}

// ---------------------------------------------------------------------------
// fp32 GEMM (kept for recurrence-internal GEMMs: q, ctx2, gi, gh)
// ---------------------------------------------------------------------------
__global__ __launch_bounds__(256) void gemm_nt_kernel(
    const float* __restrict__ A, const float* __restrict__ Bw,
    const float* __restrict__ bias, float* __restrict__ C,
    int M, int N, int Kd, int ldc)
{
    __shared__ float As[16][64];
    __shared__ float Bs[16][64];
    const int tid = threadIdx.x;
    const int tx = tid & 15, ty = tid >> 4;
    const int row0 = blockIdx.y * 64;
    const int col0 = blockIdx.x * 64;
    const int lr = tid >> 2;
    const int lk = (tid & 3) << 2;
    float acc[4][4] = {};

    for (int k0 = 0; k0 < Kd; k0 += 16) {
        float4 av = make_float4(0.f, 0.f, 0.f, 0.f);
        float4 bv = make_float4(0.f, 0.f, 0.f, 0.f);
        const int ar = row0 + lr;
        const int br = col0 + lr;
        if (ar < M) av = *reinterpret_cast<const float4*>(&A[(size_t)ar * Kd + k0 + lk]);
        if (br < N) bv = *reinterpret_cast<const float4*>(&Bw[(size_t)br * Kd + k0 + lk]);
        As[lk + 0][lr] = av.x; As[lk + 1][lr] = av.y;
        As[lk + 2][lr] = av.z; As[lk + 3][lr] = av.w;
        Bs[lk + 0][lr] = bv.x; Bs[lk + 1][lr] = bv.y;
        Bs[lk + 2][lr] = bv.z; Bs[lk + 3][lr] = bv.w;
        __syncthreads();
#pragma unroll
        for (int kk = 0; kk < 16; ++kk) {
            const float4 a = *reinterpret_cast<const float4*>(&As[kk][ty << 2]);
            const float4 b = *reinterpret_cast<const float4*>(&Bs[kk][tx << 2]);
            const float ar4[4] = {a.x, a.y, a.z, a.w};
            const float br4[4] = {b.x, b.y, b.z, b.w};
#pragma unroll
            for (int i = 0; i < 4; ++i)
#pragma unroll
                for (int j = 0; j < 4; ++j)
                    acc[i][j] = fmaf(ar4[i], br4[j], acc[i][j]);
        }
        __syncthreads();
    }

#pragma unroll
    for (int i = 0; i < 4; ++i) {
        const int row = row0 + (ty << 2) + i;
        if (row >= M) continue;
#pragma unroll
        for (int j = 0; j < 4; ++j) {
            const int col = col0 + (tx << 2) + j;
            if (col < N) C[(size_t)row * ldc + col] = acc[i][j] + bias[col];
        }
    }
}

// ---------------------------------------------------------------------------
// Additive attention (unchanged, fp32)
// ---------------------------------------------------------------------------
__global__ __launch_bounds__(256) void attn_kernel(
    const float* __restrict__ q, const float* __restrict__ kp,
    const float* __restrict__ feat, const float* __restrict__ Va,
    const float* __restrict__ bva, float* __restrict__ ctx)
{
    const int b = blockIdx.x;
    const int tid = threadIdx.x;
    const int lane = tid & 63;
    const int wave = tid >> 6;
    __shared__ float s_sc[64];
    __shared__ float s_w[64];

    float qr[8], va[8];
    const float* qb = q + (size_t)b * H_;
#pragma unroll
    for (int i = 0; i < 8; ++i) {
        qr[i] = qb[lane * 8 + i];
        va[i] = Va[lane * 8 + i];
    }

    for (int l = wave; l < L_; l += 4) {
        const float* kpl = kp + ((size_t)b * L_ + l) * H_ + lane * 8;
        float s = 0.f;
#pragma unroll
        for (int i = 0; i < 8; ++i) s += tanhf(qr[i] + kpl[i]) * va[i];
#pragma unroll
        for (int off = 32; off > 0; off >>= 1) s += __shfl_xor(s, off, 64);
        if (lane == 0) s_sc[l] = s + bva[0];
    }
    __syncthreads();

    if (wave == 0) {
        const float v = (lane < L_) ? s_sc[lane] : -1e30f;
        float m = v;
#pragma unroll
        for (int off = 32; off > 0; off >>= 1) m = fmaxf(m, __shfl_xor(m, off, 64));
        const float e = (lane < L_) ? expf(v - m) : 0.f;
        float ssum = e;
#pragma unroll
        for (int off = 32; off > 0; off >>= 1) ssum += __shfl_xor(ssum, off, 64);
        if (lane < L_) s_w[lane] = e / ssum;
    }
    __syncthreads();

#pragma unroll
    for (int r = 0; r < K_ / 256; ++r) {
        const int k = tid + r * 256;
        float acc = 0.f;
        const float* fb = feat + (size_t)b * L_ * K_ + k;
        for (int l = 0; l < L_; ++l) acc += s_w[l] * fb[(size_t)l * K_];
        ctx[(size_t)b * K_ + k] = acc;
    }
}

// ---------------------------------------------------------------------------
// x[b] = concat(emb[captions[b,t]], ctx2[b])
// ---------------------------------------------------------------------------
__global__ __launch_bounds__(256) void concat_kernel(
    const int* __restrict__ captions, int t,
    const float* __restrict__ emb, const float* __restrict__ ctx2,
    float* __restrict__ x)
{
    const int b = blockIdx.x;
    const int tid = threadIdx.x;
    const int cap = captions[(size_t)b * T_ + t];
    const int off = tid * 4;
    float4 v;
    if (off < E_) v = *reinterpret_cast<const float4*>(&emb[(size_t)cap * E_ + off]);
    else          v = *reinterpret_cast<const float4*>(&ctx2[(size_t)b * H_ + (off - E_)]);
    *reinterpret_cast<float4*>(&x[(size_t)b * (E_ + H_) + off]) = v;
}

// ---------------------------------------------------------------------------
// GRU gate fusion; writes h (fp32) and hb (bf16 copy for the out-projection).
// ---------------------------------------------------------------------------
__global__ __launch_bounds__(256) void gru_kernel(
    const float* __restrict__ gi, const float* __restrict__ gh,
    float* __restrict__ h, __hip_bfloat16* __restrict__ hb)
{
    const int idx = blockIdx.x * 256 + threadIdx.x;
    const int b = idx >> 9;
    const int j = idx & (H_ - 1);
    const size_t o = (size_t)b * 3 * H_ + j;
    const float ir = gi[o],           hr = gh[o];
    const float iz = gi[o + H_],      hz = gh[o + H_];
    const float in_ = gi[o + 2 * H_], hn = gh[o + 2 * H_];
    const float r = 1.f / (1.f + expf(-(ir + hr)));
    const float z = 1.f / (1.f + expf(-(iz + hz)));
    const float n = tanhf(in_ + r * hn);
    const float hnew = (1.f - z) * n + z * h[idx];
    h[idx] = hnew;
    hb[idx] = (__hip_bfloat16)hnew;
}

// ---------------------------------------------------------------------------
extern "C" void kernel_launch(void* const* d_in, const int* in_sizes, int n_in,
                              void* d_out, int out_size, void* d_ws, size_t ws_size,
                              hipStream_t stream)
{
    const float* features = (const float*)d_in[0];
    const int*   captions = (const int*)d_in[1];
    const float* emb  = (const float*)d_in[2];
    const float* Wq   = (const float*)d_in[3];
    const float* bq   = (const float*)d_in[4];
    const float* Uk   = (const float*)d_in[5];
    const float* bk   = (const float*)d_in[6];
    const float* Va   = (const float*)d_in[7];
    const float* bva  = (const float*)d_in[8];
    const float* W0   = (const float*)d_in[9];
    const float* b0   = (const float*)d_in[10];
    const float* Wih  = (const float*)d_in[11];
    const float* bih  = (const float*)d_in[12];
    const float* Whh  = (const float*)d_in[13];
    const float* bhh  = (const float*)d_in[14];
    const float* W1   = (const float*)d_in[15];
    const float* b1   = (const float*)d_in[16];
    float* out = (float*)d_out;

    float* ws = (float*)d_ws;
    float* kp   = ws; ws += (size_t)B_ * L_ * H_;
    float* h    = ws; ws += B_ * H_;
    float* q    = ws; ws += B_ * H_;
    float* ctx  = ws; ws += B_ * K_;
    float* ctx2 = ws; ws += B_ * H_;
    float* x    = ws; ws += B_ * (E_ + H_);
    float* gi   = ws; ws += B_ * 3 * H_;
    float* gh   = ws; ws += B_ * 3 * H_;
    __hip_bfloat16* bws = (__hip_bfloat16*)ws;
    __hip_bfloat16* feat_bf = bws; bws += (size_t)B_ * L_ * K_;   // 6.42M
    __hip_bfloat16* W1_bf   = bws; bws += (size_t)V_ * H_;        // 5.12M
    __hip_bfloat16* Uk_bf   = bws; bws += (size_t)H_ * K_;
    __hip_bfloat16* hb      = bws; bws += (size_t)B_ * H_;

    hipMemsetAsync(h, 0, (size_t)B_ * H_ * sizeof(float), stream);
    hipMemsetAsync(hb, 0, (size_t)B_ * H_ * sizeof(__hip_bfloat16), stream);

    const dim3 blk(256);

    // one-time bf16 conversions
    {
        int n4;
        n4 = B_ * L_ * K_ / 4;
        cvt_f32_bf16_kernel<<<dim3((n4 + 255) / 256), blk, 0, stream>>>(features, feat_bf, n4);
        n4 = V_ * H_ / 4;
        cvt_f32_bf16_kernel<<<dim3((n4 + 255) / 256), blk, 0, stream>>>(W1, W1_bf, n4);
        n4 = H_ * K_ / 4;
        cvt_f32_bf16_kernel<<<dim3((n4 + 255) / 256), blk, 0, stream>>>(Uk, Uk_bf, n4);
    }

    // keys_proj = features @ Uk^T + bk   [B*L, H]  (bf16 MFMA)
    gemm_bf16_nt_kernel<<<dim3(H_ / 64, (B_ * L_) / 64), blk, 0, stream>>>(
        feat_bf, Uk_bf, bk, kp, B_ * L_, H_, K_, H_);

    for (int t = 0; t < T_; ++t) {
        // q = h @ Wq^T + bq   (fp32 — recurrence path)
        gemm_nt_kernel<<<dim3(H_ / 64, B_ / 64), blk, 0, stream>>>(
            h, Wq, bq, q, B_, H_, H_, H_);
        // attention -> ctx
        attn_kernel<<<dim3(B_), blk, 0, stream>>>(q, kp, features, Va, bva, ctx);
        // ctx2 = ctx @ W0^T + b0   (fp32)
        gemm_nt_kernel<<<dim3(H_ / 64, B_ / 64), blk, 0, stream>>>(
            ctx, W0, b0, ctx2, B_, H_, K_, H_);
        // x = [emb_t, ctx2]
        concat_kernel<<<dim3(B_), blk, 0, stream>>>(captions, t, emb, ctx2, x);
        // gi = x @ Wih^T + bih   (fp32)
        gemm_nt_kernel<<<dim3(3 * H_ / 64, B_ / 64), blk, 0, stream>>>(
            x, Wih, bih, gi, B_, 3 * H_, E_ + H_, 3 * H_);
        // gh = h @ Whh^T + bhh   (fp32)
        gemm_nt_kernel<<<dim3(3 * H_ / 64, B_ / 64), blk, 0, stream>>>(
            h, Whh, bhh, gh, B_, 3 * H_, H_, 3 * H_);
        // GRU update (h fp32 + hb bf16)
        gru_kernel<<<dim3(B_ * H_ / 256), blk, 0, stream>>>(gi, gh, h, hb);
        // out_t = h @ W1^T + b1  (bf16 MFMA, leaf)
        gemm_bf16_nt_kernel<<<dim3((V_ + 63) / 64, B_ / 64), blk, 0, stream>>>(
            hb, W1_bf, b1, out + (size_t)t * V_, B_, V_, H_, T_ * V_);
    }
}

// Round 5
// 1145.743 us; speedup vs baseline: 3.2389x; 2.6256x over previous
//
#include <hip/hip_runtime.h>
#include <hip/hip_bf16.h>
#include <math.h>

#define B_ 256
#define L_ 49
#define V_ 10000
#define E_ 512
#define H_ 512
#define K_ 512
#define T_ 15

typedef __bf16 bf16x8 __attribute__((ext_vector_type(8)));
typedef float f32x4 __attribute__((ext_vector_type(4)));

#define AS1 __attribute__((address_space(1)))
#define AS3 __attribute__((address_space(3)))

// ---------------------------------------------------------------------------
// One-time fp32 -> bf16 cast (RNE), 4 elems/thread.
// ---------------------------------------------------------------------------
__global__ __launch_bounds__(256) void cvt_f32_bf16_kernel(
    const float* __restrict__ in, __hip_bfloat16* __restrict__ out, int n4)
{
    const int i = blockIdx.x * 256 + threadIdx.x;
    if (i >= n4) return;
    const float4 v = ((const float4*)in)[i];
    __hip_bfloat16 o[4];
    o[0] = (__hip_bfloat16)v.x; o[1] = (__hip_bfloat16)v.y;
    o[2] = (__hip_bfloat16)v.z; o[3] = (__hip_bfloat16)v.w;
    *(ushort4*)(out + (size_t)i * 4) = *(ushort4*)o;
}

// ---------------------------------------------------------------------------
// Embedding gather + cast: out[t*B+b, :] = bf16(emb[captions[b,t], :])
// one block per row (128 thr x 4 elems = 512).
// ---------------------------------------------------------------------------
__global__ __launch_bounds__(128) void emb_gather_kernel(
    const int* __restrict__ caps, const float* __restrict__ emb,
    __hip_bfloat16* __restrict__ out)
{
    const int r = blockIdx.x;          // 0 .. T_*B_-1
    const int t = r >> 8;              // B_ == 256
    const int b = r & 255;
    const int cap = caps[(size_t)b * T_ + t];
    const int e = threadIdx.x * 4;
    const float4 v = *(const float4*)(emb + (size_t)cap * E_ + e);
    __hip_bfloat16 o[4];
    o[0] = (__hip_bfloat16)v.x; o[1] = (__hip_bfloat16)v.y;
    o[2] = (__hip_bfloat16)v.z; o[3] = (__hip_bfloat16)v.w;
    *(ushort4*)(out + (size_t)r * E_ + e) = *(ushort4*)o;
}

// ---------------------------------------------------------------------------
// bf16 MFMA GEMM (NT): C[M,N] = A[M,Kd] @ Bw[N,Kd]^T (+bias[N]) (+Cin[M,N]).
// 64x64 tile, BK=64, 4 waves (2x2), 2x2 mfma_f32_16x16x32_bf16 per wave.
// global_load_lds(16B) staging, linear LDS, m97 2-barrier loop.
// M%64==0, Kd%64==0, lda/ldb %8==0 required; N tail guarded.
// OutT = float or __hip_bfloat16.
// ---------------------------------------------------------------------------
template <typename OutT>
__global__ __launch_bounds__(256) void gemm_bf16_nt_kernel(
    const __hip_bfloat16* __restrict__ A, const __hip_bfloat16* __restrict__ Bw,
    const float* __restrict__ bias, const float* __restrict__ Cin, int ldcin,
    OutT* __restrict__ C, int M, int N, int Kd, int lda, int ldb, int ldc)
{
    __shared__ __hip_bfloat16 Asl[64 * 64];
    __shared__ __hip_bfloat16 Bsl[64 * 64];
    const int tid  = threadIdx.x;
    const int lane = tid & 63;
    const int w    = tid >> 6;
    const int wm   = w >> 1, wn = w & 1;
    const int row0 = blockIdx.y * 64;
    const int col0 = blockIdx.x * 64;

    const int srow = tid >> 3;          // 0..31 (+32 on 2nd issue)
    const int scol = (tid & 7) << 3;    // 0..56

    const int lr = lane & 15;
    const int lk = (lane >> 4) << 3;

    f32x4 acc[2][2] = {};

    const __hip_bfloat16* gA0 = A + (size_t)(row0 + srow) * lda + scol;
    const __hip_bfloat16* gA1 = gA0 + (size_t)32 * lda;
    const int br0 = col0 + srow, br1 = br0 + 32;
    const __hip_bfloat16* gB0 = Bw + (size_t)br0 * ldb + scol;
    const __hip_bfloat16* gB1 = gB0 + (size_t)32 * ldb;
    const bool v0 = br0 < N, v1 = br1 < N;

    for (int k0 = 0; k0 < Kd; k0 += 64) {
        __syncthreads();
        __builtin_amdgcn_global_load_lds((const AS1 void*)(gA0 + k0),
            (AS3 void*)(Asl + tid * 8), 16, 0, 0);
        __builtin_amdgcn_global_load_lds((const AS1 void*)(gA1 + k0),
            (AS3 void*)(Asl + 2048 + tid * 8), 16, 0, 0);
        if (v0) __builtin_amdgcn_global_load_lds((const AS1 void*)(gB0 + k0),
            (AS3 void*)(Bsl + tid * 8), 16, 0, 0);
        if (v1) __builtin_amdgcn_global_load_lds((const AS1 void*)(gB1 + k0),
            (AS3 void*)(Bsl + 2048 + tid * 8), 16, 0, 0);
        __syncthreads();

#pragma unroll
        for (int ks = 0; ks < 2; ++ks) {
            bf16x8 af[2], bfr[2];
#pragma unroll
            for (int i = 0; i < 2; ++i)
                af[i] = *(const bf16x8*)(Asl + (wm * 32 + i * 16 + lr) * 64 + ks * 32 + lk);
#pragma unroll
            for (int j = 0; j < 2; ++j)
                bfr[j] = *(const bf16x8*)(Bsl + (wn * 32 + j * 16 + lr) * 64 + ks * 32 + lk);
#pragma unroll
            for (int i = 0; i < 2; ++i)
#pragma unroll
                for (int j = 0; j < 2; ++j)
                    acc[i][j] = __builtin_amdgcn_mfma_f32_16x16x32_bf16(
                        af[i], bfr[j], acc[i][j], 0, 0, 0);
        }
    }

    // C/D layout: col = lane&15, row = (lane>>4)*4 + reg  [m89-verified]
    const int orow = (lane >> 4) << 2;
#pragma unroll
    for (int i = 0; i < 2; ++i) {
#pragma unroll
        for (int j = 0; j < 2; ++j) {
            const int col = col0 + wn * 32 + j * 16 + lr;
            if (col >= N) continue;
            const float bv = bias ? bias[col] : 0.f;
            const int rowb = row0 + wm * 32 + i * 16 + orow;
#pragma unroll
            for (int r = 0; r < 4; ++r) {
                float v = acc[i][j][r] + bv;
                if (Cin) v += Cin[(size_t)(rowb + r) * ldcin + col];
                C[(size_t)(rowb + r) * ldc + col] = (OutT)v;
            }
        }
    }
}

// ---------------------------------------------------------------------------
// Additive attention. q fp32, kp bf16, feat fp32 -> ctx bf16.
// ---------------------------------------------------------------------------
__global__ __launch_bounds__(256) void attn_kernel(
    const float* __restrict__ q, const __hip_bfloat16* __restrict__ kp,
    const float* __restrict__ feat, const float* __restrict__ Va,
    const float* __restrict__ bva, __hip_bfloat16* __restrict__ ctx)
{
    const int b = blockIdx.x;
    const int tid = threadIdx.x;
    const int lane = tid & 63;
    const int wave = tid >> 6;
    __shared__ float s_sc[64];
    __shared__ float s_w[64];

    float qr[8], va[8];
    const float* qb = q + (size_t)b * H_;
#pragma unroll
    for (int i = 0; i < 8; ++i) {
        qr[i] = qb[lane * 8 + i];
        va[i] = Va[lane * 8 + i];
    }

    for (int l = wave; l < L_; l += 4) {
        const bf16x8 kv = *(const bf16x8*)(kp + ((size_t)b * L_ + l) * H_ + lane * 8);
        float s = 0.f;
#pragma unroll
        for (int i = 0; i < 8; ++i) s += tanhf(qr[i] + (float)kv[i]) * va[i];
#pragma unroll
        for (int off = 32; off > 0; off >>= 1) s += __shfl_xor(s, off, 64);
        if (lane == 0) s_sc[l] = s + bva[0];
    }
    __syncthreads();

    if (wave == 0) {
        const float v = (lane < L_) ? s_sc[lane] : -1e30f;
        float m = v;
#pragma unroll
        for (int off = 32; off > 0; off >>= 1) m = fmaxf(m, __shfl_xor(m, off, 64));
        const float e = (lane < L_) ? expf(v - m) : 0.f;
        float ssum = e;
#pragma unroll
        for (int off = 32; off > 0; off >>= 1) ssum += __shfl_xor(ssum, off, 64);
        if (lane < L_) s_w[lane] = e / ssum;
    }
    __syncthreads();

#pragma unroll
    for (int r = 0; r < K_ / 256; ++r) {
        const int k = tid + r * 256;
        float acc = 0.f;
        const float* fb = feat + (size_t)b * L_ * K_ + k;
        for (int l = 0; l < L_; ++l) acc += s_w[l] * fb[(size_t)l * K_];
        ctx[(size_t)b * K_ + k] = (__hip_bfloat16)acc;
    }
}

// ---------------------------------------------------------------------------
// GRU gate fusion; h fp32 state + hb bf16 shadow.
// ---------------------------------------------------------------------------
__global__ __launch_bounds__(256) void gru_kernel(
    const float* __restrict__ gi, const float* __restrict__ gh,
    float* __restrict__ h, __hip_bfloat16* __restrict__ hb)
{
    const int idx = blockIdx.x * 256 + threadIdx.x;
    const int b = idx >> 9;
    const int j = idx & (H_ - 1);
    const size_t o = (size_t)b * 3 * H_ + j;
    const float ir = gi[o],           hr = gh[o];
    const float iz = gi[o + H_],      hz = gh[o + H_];
    const float in_ = gi[o + 2 * H_], hn = gh[o + 2 * H_];
    const float r = 1.f / (1.f + expf(-(ir + hr)));
    const float z = 1.f / (1.f + expf(-(iz + hz)));
    const float n = tanhf(in_ + r * hn);
    const float hnew = (1.f - z) * n + z * h[idx];
    h[idx] = hnew;
    hb[idx] = (__hip_bfloat16)hnew;
}

// ---------------------------------------------------------------------------
extern "C" void kernel_launch(void* const* d_in, const int* in_sizes, int n_in,
                              void* d_out, int out_size, void* d_ws, size_t ws_size,
                              hipStream_t stream)
{
    const float* features = (const float*)d_in[0];
    const int*   captions = (const int*)d_in[1];
    const float* emb  = (const float*)d_in[2];
    const float* Wq   = (const float*)d_in[3];
    const float* bq   = (const float*)d_in[4];
    const float* Uk   = (const float*)d_in[5];
    const float* bk   = (const float*)d_in[6];
    const float* Va   = (const float*)d_in[7];
    const float* bva  = (const float*)d_in[8];
    const float* W0   = (const float*)d_in[9];
    const float* b0   = (const float*)d_in[10];
    const float* Wih  = (const float*)d_in[11];
    const float* bih  = (const float*)d_in[12];
    const float* Whh  = (const float*)d_in[13];
    const float* bhh  = (const float*)d_in[14];
    const float* W1   = (const float*)d_in[15];
    const float* b1   = (const float*)d_in[16];
    float* out = (float*)d_out;

    // fp32 scratch
    float* ws = (float*)d_ws;
    float* h      = ws; ws += B_ * H_;
    float* q      = ws; ws += B_ * H_;
    float* gi     = ws; ws += B_ * 3 * H_;
    float* gh     = ws; ws += B_ * 3 * H_;
    float* gi_emb = ws; ws += (size_t)T_ * B_ * 3 * H_;   // 5.9M floats
    // bf16 scratch
    __hip_bfloat16* bws = (__hip_bfloat16*)ws;
    __hip_bfloat16* feat_bf = bws; bws += (size_t)B_ * L_ * K_;
    __hip_bfloat16* kp_bf   = bws; bws += (size_t)B_ * L_ * H_;
    __hip_bfloat16* W1_bf   = bws; bws += (size_t)V_ * H_;
    __hip_bfloat16* Uk_bf   = bws; bws += (size_t)H_ * K_;
    __hip_bfloat16* Wq_bf   = bws; bws += (size_t)H_ * H_;
    __hip_bfloat16* W0_bf   = bws; bws += (size_t)H_ * K_;
    __hip_bfloat16* Wih_bf  = bws; bws += (size_t)3 * H_ * (E_ + H_);
    __hip_bfloat16* Whh_bf  = bws; bws += (size_t)3 * H_ * H_;
    __hip_bfloat16* emb_all = bws; bws += (size_t)T_ * B_ * E_;
    __hip_bfloat16* hb      = bws; bws += (size_t)B_ * H_;
    __hip_bfloat16* ctx_bf  = bws; bws += (size_t)B_ * K_;
    __hip_bfloat16* ctx2_bf = bws; bws += (size_t)B_ * H_;

    hipMemsetAsync(h, 0, (size_t)B_ * H_ * sizeof(float), stream);
    hipMemsetAsync(hb, 0, (size_t)B_ * H_ * sizeof(__hip_bfloat16), stream);

    const dim3 blk(256);
    auto cvt = [&](const float* src, __hip_bfloat16* dst, size_t n) {
        const int n4 = (int)(n / 4);
        cvt_f32_bf16_kernel<<<dim3((n4 + 255) / 256), blk, 0, stream>>>(src, dst, n4);
    };

    // ---- prologue: one-time casts + recurrence-independent GEMMs ----
    cvt(features, feat_bf, (size_t)B_ * L_ * K_);
    cvt(W1, W1_bf, (size_t)V_ * H_);
    cvt(Uk, Uk_bf, (size_t)H_ * K_);
    cvt(Wq, Wq_bf, (size_t)H_ * H_);
    cvt(W0, W0_bf, (size_t)H_ * K_);
    cvt(Wih, Wih_bf, (size_t)3 * H_ * (E_ + H_));
    cvt(Whh, Whh_bf, (size_t)3 * H_ * H_);
    emb_gather_kernel<<<dim3(T_ * B_), dim3(128), 0, stream>>>(captions, emb, emb_all);

    // keys_proj = features @ Uk^T + bk  -> bf16 [B*L, H]
    gemm_bf16_nt_kernel<__hip_bfloat16><<<dim3(H_ / 64, (B_ * L_) / 64), blk, 0, stream>>>(
        feat_bf, Uk_bf, bk, nullptr, 0, kp_bf, B_ * L_, H_, K_, K_, K_, H_);

    // gi_emb[t*B+b, :] = emb_t @ Wih[:, :E]^T + bih   (all T at once)
    gemm_bf16_nt_kernel<float><<<dim3(3 * H_ / 64, (T_ * B_) / 64), blk, 0, stream>>>(
        emb_all, Wih_bf, bih, nullptr, 0, gi_emb, T_ * B_, 3 * H_, E_,
        E_, E_ + H_, 3 * H_);

    // ---- recurrence ----
    for (int t = 0; t < T_; ++t) {
        // q = h @ Wq^T + bq  (fp32 out)
        gemm_bf16_nt_kernel<float><<<dim3(H_ / 64, B_ / 64), blk, 0, stream>>>(
            hb, Wq_bf, bq, nullptr, 0, q, B_, H_, H_, H_, H_, H_);
        // attention -> ctx (bf16)
        attn_kernel<<<dim3(B_), blk, 0, stream>>>(q, kp_bf, features, Va, bva, ctx_bf);
        // ctx2 = ctx @ W0^T + b0  (bf16 out)
        gemm_bf16_nt_kernel<__hip_bfloat16><<<dim3(H_ / 64, B_ / 64), blk, 0, stream>>>(
            ctx_bf, W0_bf, b0, nullptr, 0, ctx2_bf, B_, H_, K_, K_, K_, H_);
        // gi = gi_emb[t] + ctx2 @ Wih[:, E:]^T
        gemm_bf16_nt_kernel<float><<<dim3(3 * H_ / 64, B_ / 64), blk, 0, stream>>>(
            ctx2_bf, Wih_bf + E_, nullptr, gi_emb + (size_t)t * B_ * 3 * H_, 3 * H_,
            gi, B_, 3 * H_, H_, H_, E_ + H_, 3 * H_);
        // gh = h @ Whh^T + bhh
        gemm_bf16_nt_kernel<float><<<dim3(3 * H_ / 64, B_ / 64), blk, 0, stream>>>(
            hb, Whh_bf, bhh, nullptr, 0, gh, B_, 3 * H_, H_, H_, H_, 3 * H_);
        // GRU update
        gru_kernel<<<dim3(B_ * H_ / 256), blk, 0, stream>>>(gi, gh, h, hb);
        // out_t = h @ W1^T + b1
        gemm_bf16_nt_kernel<float><<<dim3((V_ + 63) / 64, B_ / 64), blk, 0, stream>>>(
            hb, W1_bf, b1, nullptr, 0, out + (size_t)t * V_, B_, V_, H_, H_, H_, T_ * V_);
    }
}

// Round 6
// 1065.015 us; speedup vs baseline: 3.4844x; 1.0758x over previous
//
#include <hip/hip_runtime.h>
#include <hip/hip_bf16.h>
#include <math.h>

#define B_ 256
#define L_ 49
#define V_ 10000
#define E_ 512
#define H_ 512
#define K_ 512
#define T_ 15

typedef __bf16 bf16x8 __attribute__((ext_vector_type(8)));
typedef float f32x4 __attribute__((ext_vector_type(4)));

#define AS1 __attribute__((address_space(1)))
#define AS3 __attribute__((address_space(3)))

// ---------------------------------------------------------------------------
// fp32 -> bf16 cast (RNE), 4 elems/thread.
// ---------------------------------------------------------------------------
__global__ __launch_bounds__(256) void cvt_f32_bf16_kernel(
    const float* __restrict__ in, __hip_bfloat16* __restrict__ out, int n4)
{
    const int i = blockIdx.x * 256 + threadIdx.x;
    if (i >= n4) return;
    const float4 v = ((const float4*)in)[i];
    __hip_bfloat16 o[4];
    o[0] = (__hip_bfloat16)v.x; o[1] = (__hip_bfloat16)v.y;
    o[2] = (__hip_bfloat16)v.z; o[3] = (__hip_bfloat16)v.w;
    *(ushort4*)(out + (size_t)i * 4) = *(ushort4*)o;
}

// ---------------------------------------------------------------------------
// Transpose + cast: out[c*R + r] = bf16(in[r*C + c]). 32x32 LDS tiles.
// grid (C/32, R/32), 256 threads.
// ---------------------------------------------------------------------------
__global__ __launch_bounds__(256) void transpose_cast_kernel(
    const float* __restrict__ in, __hip_bfloat16* __restrict__ out, int R, int Cc)
{
    __shared__ float tile[32][33];
    const int tr0 = blockIdx.y * 32, tc0 = blockIdx.x * 32;
    const int tx = threadIdx.x & 31, ty = threadIdx.x >> 5;   // 8 rows/pass
#pragma unroll
    for (int i = 0; i < 32; i += 8)
        tile[ty + i][tx] = in[(size_t)(tr0 + ty + i) * Cc + tc0 + tx];
    __syncthreads();
#pragma unroll
    for (int i = 0; i < 32; i += 8)
        out[(size_t)(tc0 + ty + i) * R + tr0 + tx] = (__hip_bfloat16)tile[tx][ty + i];
}

// ---------------------------------------------------------------------------
// bfull[i] = bih[i] + dot(Wih[i, E:], b0)   (fp32, i < 3H)
// ---------------------------------------------------------------------------
__global__ __launch_bounds__(256) void bfull_kernel(
    const float* __restrict__ Wih, const float* __restrict__ b0,
    const float* __restrict__ bih, float* __restrict__ bfull)
{
    const int i = blockIdx.x * 256 + threadIdx.x;
    if (i >= 3 * H_) return;
    const float* wrow = Wih + (size_t)i * (E_ + H_) + E_;
    float acc = bih[i];
    for (int j = 0; j < H_; ++j) acc += wrow[j] * b0[j];
    bfull[i] = acc;
}

// ---------------------------------------------------------------------------
// Embedding gather + cast: out[t*B+b, :] = bf16(emb[captions[b,t], :])
// ---------------------------------------------------------------------------
__global__ __launch_bounds__(128) void emb_gather_kernel(
    const int* __restrict__ caps, const float* __restrict__ emb,
    __hip_bfloat16* __restrict__ out)
{
    const int r = blockIdx.x;          // 0 .. T_*B_-1
    const int t = r >> 8;              // B_ == 256
    const int b = r & 255;
    const int cap = caps[(size_t)b * T_ + t];
    const int e = threadIdx.x * 4;
    const float4 v = *(const float4*)(emb + (size_t)cap * E_ + e);
    __hip_bfloat16 o[4];
    o[0] = (__hip_bfloat16)v.x; o[1] = (__hip_bfloat16)v.y;
    o[2] = (__hip_bfloat16)v.z; o[3] = (__hip_bfloat16)v.w;
    *(ushort4*)(out + (size_t)r * E_ + e) = *(ushort4*)o;
}

// ---------------------------------------------------------------------------
// bf16 MFMA GEMM body (NT): C[M,N] = A[M,Kd] @ Bw[N,Kd]^T (+bias) (+Cin).
// 64x64 tile, BK=64, 4 waves (2x2), 2x2 mfma_f32_16x16x32_bf16 per wave.
// global_load_lds(16B) staging, linear LDS, m97 2-barrier loop.
// M%64==0, Kd%64==0, lda/ldb %8==0; N tail guarded.
// ---------------------------------------------------------------------------
template <typename OutT>
__device__ __forceinline__ void gemm_nt_body(
    const __hip_bfloat16* __restrict__ A, const __hip_bfloat16* __restrict__ Bw,
    const float* __restrict__ bias, const float* __restrict__ Cin, int ldcin,
    OutT* __restrict__ C, int M, int N, int Kd, int lda, int ldb, int ldc,
    int bx, int by)
{
    __shared__ __hip_bfloat16 Asl[64 * 64];
    __shared__ __hip_bfloat16 Bsl[64 * 64];
    const int tid  = threadIdx.x;
    const int lane = tid & 63;
    const int w    = tid >> 6;
    const int wm   = w >> 1, wn = w & 1;
    const int row0 = by * 64;
    const int col0 = bx * 64;

    const int srow = tid >> 3;
    const int scol = (tid & 7) << 3;

    const int lr = lane & 15;
    const int lk = (lane >> 4) << 3;

    f32x4 acc[2][2] = {};

    const __hip_bfloat16* gA0 = A + (size_t)(row0 + srow) * lda + scol;
    const __hip_bfloat16* gA1 = gA0 + (size_t)32 * lda;
    const int br0 = col0 + srow, br1 = br0 + 32;
    const __hip_bfloat16* gB0 = Bw + (size_t)br0 * ldb + scol;
    const __hip_bfloat16* gB1 = gB0 + (size_t)32 * ldb;
    const bool v0 = br0 < N, v1 = br1 < N;

    for (int k0 = 0; k0 < Kd; k0 += 64) {
        __syncthreads();
        __builtin_amdgcn_global_load_lds((const AS1 void*)(gA0 + k0),
            (AS3 void*)(Asl + tid * 8), 16, 0, 0);
        __builtin_amdgcn_global_load_lds((const AS1 void*)(gA1 + k0),
            (AS3 void*)(Asl + 2048 + tid * 8), 16, 0, 0);
        if (v0) __builtin_amdgcn_global_load_lds((const AS1 void*)(gB0 + k0),
            (AS3 void*)(Bsl + tid * 8), 16, 0, 0);
        if (v1) __builtin_amdgcn_global_load_lds((const AS1 void*)(gB1 + k0),
            (AS3 void*)(Bsl + 2048 + tid * 8), 16, 0, 0);
        __syncthreads();

#pragma unroll
        for (int ks = 0; ks < 2; ++ks) {
            bf16x8 af[2], bfr[2];
#pragma unroll
            for (int i = 0; i < 2; ++i)
                af[i] = *(const bf16x8*)(Asl + (wm * 32 + i * 16 + lr) * 64 + ks * 32 + lk);
#pragma unroll
            for (int j = 0; j < 2; ++j)
                bfr[j] = *(const bf16x8*)(Bsl + (wn * 32 + j * 16 + lr) * 64 + ks * 32 + lk);
#pragma unroll
            for (int i = 0; i < 2; ++i)
#pragma unroll
                for (int j = 0; j < 2; ++j)
                    acc[i][j] = __builtin_amdgcn_mfma_f32_16x16x32_bf16(
                        af[i], bfr[j], acc[i][j], 0, 0, 0);
        }
    }

    // C/D layout: col = lane&15, row = (lane>>4)*4 + reg  [m89-verified]
    const int orow = (lane >> 4) << 2;
#pragma unroll
    for (int i = 0; i < 2; ++i) {
#pragma unroll
        for (int j = 0; j < 2; ++j) {
            const int col = col0 + wn * 32 + j * 16 + lr;
            if (col >= N) continue;
            const float bv = bias ? bias[col] : 0.f;
            const int rowb = row0 + wm * 32 + i * 16 + orow;
#pragma unroll
            for (int r = 0; r < 4; ++r) {
                float v = acc[i][j][r] + bv;
                if (Cin) v += Cin[(size_t)(rowb + r) * ldcin + col];
                C[(size_t)(rowb + r) * ldc + col] = (OutT)v;
            }
        }
    }
}

template <typename OutT>
__global__ __launch_bounds__(256) void gemm_bf16_nt_kernel(
    const __hip_bfloat16* __restrict__ A, const __hip_bfloat16* __restrict__ Bw,
    const float* __restrict__ bias, const float* __restrict__ Cin, int ldcin,
    OutT* __restrict__ C, int M, int N, int Kd, int lda, int ldb, int ldc)
{
    gemm_nt_body<OutT>(A, Bw, bias, Cin, ldcin, C, M, N, Kd, lda, ldb, ldc,
                       blockIdx.x, blockIdx.y);
}

// ---------------------------------------------------------------------------
// Fused gi+gh: z==0: gi = ctx @ Wfused^T + gi_emb_t ; z==1: gh = hb @ Whh^T + bhh
// grid (24, 4, 2)
// ---------------------------------------------------------------------------
__global__ __launch_bounds__(256) void gemm_gigh_kernel(
    const __hip_bfloat16* __restrict__ ctx, const __hip_bfloat16* __restrict__ Wf,
    const float* __restrict__ gi_emb_t,
    const __hip_bfloat16* __restrict__ hb, const __hip_bfloat16* __restrict__ Whh,
    const float* __restrict__ bhh,
    float* __restrict__ gi, float* __restrict__ gh)
{
    if (blockIdx.z == 0)
        gemm_nt_body<float>(ctx, Wf, nullptr, gi_emb_t, 3 * H_, gi,
                            B_, 3 * H_, K_, K_, K_, 3 * H_, blockIdx.x, blockIdx.y);
    else
        gemm_nt_body<float>(hb, Whh, bhh, nullptr, 0, gh,
                            B_, 3 * H_, H_, H_, H_, 3 * H_, blockIdx.x, blockIdx.y);
}

// ---------------------------------------------------------------------------
// Fused q + additive attention. One block per b.
// Phase 1: q = hb[b] @ Wq^T + bq  (WqT bf16, coalesced)  -> LDS
// Phase 2: scores + softmax + ctx (feat bf16) -> ctx bf16
// ---------------------------------------------------------------------------
__global__ __launch_bounds__(256) void attn_fused_kernel(
    const __hip_bfloat16* __restrict__ hb, const __hip_bfloat16* __restrict__ WqT,
    const float* __restrict__ bq, const __hip_bfloat16* __restrict__ kp,
    const __hip_bfloat16* __restrict__ feat, const float* __restrict__ Va,
    const float* __restrict__ bva, __hip_bfloat16* __restrict__ ctx)
{
    const int b = blockIdx.x;
    const int tid = threadIdx.x;
    const int lane = tid & 63;
    const int wave = tid >> 6;
    __shared__ float hb_s[H_];
    __shared__ float q_s[H_];
    __shared__ float s_sc[64];
    __shared__ float s_w[64];

    // stage h row as f32
    {
        const __hip_bfloat16* hrow = hb + (size_t)b * H_;
        hb_s[tid * 2]     = (float)hrow[tid * 2];
        hb_s[tid * 2 + 1] = (float)hrow[tid * 2 + 1];
    }
    __syncthreads();

    // q[j] for j = 2*tid, 2*tid+1 (WqT is [K=512 rows][H cols], row k holds Wq[:,k])
    {
        float a0 = bq[2 * tid], a1 = bq[2 * tid + 1];
        for (int k = 0; k < H_; ++k) {
            const float hv = hb_s[k];
            const __hip_bfloat16* wr = WqT + (size_t)k * H_ + 2 * tid;
            a0 += hv * (float)wr[0];
            a1 += hv * (float)wr[1];
        }
        q_s[2 * tid] = a0;
        q_s[2 * tid + 1] = a1;
    }
    __syncthreads();

    float qr[8], va[8];
#pragma unroll
    for (int i = 0; i < 8; ++i) {
        qr[i] = q_s[lane * 8 + i];
        va[i] = Va[lane * 8 + i];
    }

    for (int l = wave; l < L_; l += 4) {
        const bf16x8 kv = *(const bf16x8*)(kp + ((size_t)b * L_ + l) * H_ + lane * 8);
        float s = 0.f;
#pragma unroll
        for (int i = 0; i < 8; ++i) s += tanhf(qr[i] + (float)kv[i]) * va[i];
#pragma unroll
        for (int off = 32; off > 0; off >>= 1) s += __shfl_xor(s, off, 64);
        if (lane == 0) s_sc[l] = s + bva[0];
    }
    __syncthreads();

    if (wave == 0) {
        const float v = (lane < L_) ? s_sc[lane] : -1e30f;
        float m = v;
#pragma unroll
        for (int off = 32; off > 0; off >>= 1) m = fmaxf(m, __shfl_xor(m, off, 64));
        const float e = (lane < L_) ? expf(v - m) : 0.f;
        float ssum = e;
#pragma unroll
        for (int off = 32; off > 0; off >>= 1) ssum += __shfl_xor(ssum, off, 64);
        if (lane < L_) s_w[lane] = e / ssum;
    }
    __syncthreads();

#pragma unroll
    for (int r = 0; r < 2; ++r) {
        const int k = tid + r * 256;
        float acc = 0.f;
        const __hip_bfloat16* fb = feat + (size_t)b * L_ * K_ + k;
        for (int l = 0; l < L_; ++l) acc += s_w[l] * (float)fb[(size_t)l * K_];
        ctx[(size_t)b * K_ + k] = (__hip_bfloat16)acc;
    }
}

// ---------------------------------------------------------------------------
// GRU gate fusion; h fp32 state, hb bf16 shadow, h_all[b*T+t] bf16 history.
// ---------------------------------------------------------------------------
__global__ __launch_bounds__(256) void gru_kernel(
    const float* __restrict__ gi, const float* __restrict__ gh,
    float* __restrict__ h, __hip_bfloat16* __restrict__ hb,
    __hip_bfloat16* __restrict__ h_all, int t)
{
    const int idx = blockIdx.x * 256 + threadIdx.x;
    const int b = idx >> 9;
    const int j = idx & (H_ - 1);
    const size_t o = (size_t)b * 3 * H_ + j;
    const float ir = gi[o],           hr = gh[o];
    const float iz = gi[o + H_],      hz = gh[o + H_];
    const float in_ = gi[o + 2 * H_], hn = gh[o + 2 * H_];
    const float r = 1.f / (1.f + expf(-(ir + hr)));
    const float z = 1.f / (1.f + expf(-(iz + hz)));
    const float n = tanhf(in_ + r * hn);
    const float hnew = (1.f - z) * n + z * h[idx];
    h[idx] = hnew;
    const __hip_bfloat16 hv = (__hip_bfloat16)hnew;
    hb[idx] = hv;
    h_all[((size_t)b * T_ + t) * H_ + j] = hv;
}

// ---------------------------------------------------------------------------
extern "C" void kernel_launch(void* const* d_in, const int* in_sizes, int n_in,
                              void* d_out, int out_size, void* d_ws, size_t ws_size,
                              hipStream_t stream)
{
    const float* features = (const float*)d_in[0];
    const int*   captions = (const int*)d_in[1];
    const float* emb  = (const float*)d_in[2];
    const float* Wq   = (const float*)d_in[3];
    const float* bq   = (const float*)d_in[4];
    const float* Uk   = (const float*)d_in[5];
    const float* bk   = (const float*)d_in[6];
    const float* Va   = (const float*)d_in[7];
    const float* bva  = (const float*)d_in[8];
    const float* W0   = (const float*)d_in[9];
    const float* b0   = (const float*)d_in[10];
    const float* Wih  = (const float*)d_in[11];
    const float* bih  = (const float*)d_in[12];
    const float* Whh  = (const float*)d_in[13];
    const float* bhh  = (const float*)d_in[14];
    const float* W1   = (const float*)d_in[15];
    const float* b1   = (const float*)d_in[16];
    float* out = (float*)d_out;

    // fp32 scratch
    float* ws = (float*)d_ws;
    float* h      = ws; ws += B_ * H_;
    float* gi     = ws; ws += B_ * 3 * H_;
    float* gh     = ws; ws += B_ * 3 * H_;
    float* bfull  = ws; ws += 3 * H_;
    float* gi_emb = ws; ws += (size_t)T_ * B_ * 3 * H_;
    // bf16 scratch
    __hip_bfloat16* bws = (__hip_bfloat16*)ws;
    __hip_bfloat16* feat_bf = bws; bws += (size_t)B_ * L_ * K_;
    __hip_bfloat16* kp_bf   = bws; bws += (size_t)B_ * L_ * H_;
    __hip_bfloat16* W1_bf   = bws; bws += (size_t)V_ * H_;
    __hip_bfloat16* Uk_bf   = bws; bws += (size_t)H_ * K_;
    __hip_bfloat16* WqT_bf  = bws; bws += (size_t)H_ * H_;
    __hip_bfloat16* W0T_bf  = bws; bws += (size_t)K_ * H_;
    __hip_bfloat16* Wih_bf  = bws; bws += (size_t)3 * H_ * (E_ + H_);
    __hip_bfloat16* Whh_bf  = bws; bws += (size_t)3 * H_ * H_;
    __hip_bfloat16* Wfused  = bws; bws += (size_t)3 * H_ * K_;
    __hip_bfloat16* emb_all = bws; bws += (size_t)T_ * B_ * E_;
    __hip_bfloat16* hb      = bws; bws += (size_t)B_ * H_;
    __hip_bfloat16* ctx_bf  = bws; bws += (size_t)B_ * K_;
    __hip_bfloat16* h_all   = bws; bws += (size_t)B_ * T_ * H_;

    hipMemsetAsync(h, 0, (size_t)B_ * H_ * sizeof(float), stream);
    hipMemsetAsync(hb, 0, (size_t)B_ * H_ * sizeof(__hip_bfloat16), stream);

    const dim3 blk(256);
    auto cvt = [&](const float* src, __hip_bfloat16* dst, size_t n) {
        const int n4 = (int)(n / 4);
        cvt_f32_bf16_kernel<<<dim3((n4 + 255) / 256), blk, 0, stream>>>(src, dst, n4);
    };

    // ---- prologue: casts, transposes, recurrence-independent GEMMs ----
    cvt(features, feat_bf, (size_t)B_ * L_ * K_);
    cvt(W1, W1_bf, (size_t)V_ * H_);
    cvt(Uk, Uk_bf, (size_t)H_ * K_);
    cvt(Wih, Wih_bf, (size_t)3 * H_ * (E_ + H_));
    cvt(Whh, Whh_bf, (size_t)3 * H_ * H_);
    transpose_cast_kernel<<<dim3(H_ / 32, H_ / 32), blk, 0, stream>>>(Wq, WqT_bf, H_, H_);
    transpose_cast_kernel<<<dim3(K_ / 32, H_ / 32), blk, 0, stream>>>(W0, W0T_bf, H_, K_);
    bfull_kernel<<<dim3((3 * H_ + 255) / 256), blk, 0, stream>>>(Wih, b0, bih, bfull);
    emb_gather_kernel<<<dim3(T_ * B_), dim3(128), 0, stream>>>(captions, emb, emb_all);

    // keys_proj = features @ Uk^T + bk  -> bf16 [B*L, H]
    gemm_bf16_nt_kernel<__hip_bfloat16><<<dim3(H_ / 64, (B_ * L_) / 64), blk, 0, stream>>>(
        feat_bf, Uk_bf, bk, nullptr, 0, kp_bf, B_ * L_, H_, K_, K_, K_, H_);

    // Wfused[3H, K] = Wih[:, E:] @ W0  (NT with W0^T as Bw)
    gemm_bf16_nt_kernel<__hip_bfloat16><<<dim3(K_ / 64, 3 * H_ / 64), blk, 0, stream>>>(
        Wih_bf + E_, W0T_bf, nullptr, nullptr, 0, Wfused, 3 * H_, K_, H_,
        E_ + H_, H_, K_);

    // gi_emb[t*B+b, :] = emb_t @ Wih[:, :E]^T + (bih + WihE @ b0)
    gemm_bf16_nt_kernel<float><<<dim3(3 * H_ / 64, (T_ * B_) / 64), blk, 0, stream>>>(
        emb_all, Wih_bf, bfull, nullptr, 0, gi_emb, T_ * B_, 3 * H_, E_,
        E_, E_ + H_, 3 * H_);

    // ---- recurrence: 3 dispatches per step ----
    for (int t = 0; t < T_; ++t) {
        attn_fused_kernel<<<dim3(B_), blk, 0, stream>>>(
            hb, WqT_bf, bq, kp_bf, feat_bf, Va, bva, ctx_bf);
        gemm_gigh_kernel<<<dim3(3 * H_ / 64, B_ / 64, 2), blk, 0, stream>>>(
            ctx_bf, Wfused, gi_emb + (size_t)t * B_ * 3 * H_,
            hb, Whh_bf, bhh, gi, gh);
        gru_kernel<<<dim3(B_ * H_ / 256), blk, 0, stream>>>(gi, gh, h, hb, h_all, t);
    }

    // ---- epilogue: one big out-projection over all T ----
    // out[b, t, :] = h_all[b*T+t] @ W1^T + b1   (ldc = V, rows contiguous)
    gemm_bf16_nt_kernel<float><<<dim3((V_ + 63) / 64, (B_ * T_) / 64), blk, 0, stream>>>(
        h_all, W1_bf, b1, nullptr, 0, out, B_ * T_, V_, H_, H_, H_, V_);
}

// Round 7
// 1006.281 us; speedup vs baseline: 3.6878x; 1.0584x over previous
//
#include <hip/hip_runtime.h>
#include <hip/hip_bf16.h>
#include <math.h>

#define B_ 256
#define L_ 49
#define V_ 10000
#define E_ 512
#define H_ 512
#define K_ 512
#define T_ 15

typedef __bf16 bf16x8 __attribute__((ext_vector_type(8)));
typedef float f32x4 __attribute__((ext_vector_type(4)));

#define AS1 __attribute__((address_space(1)))
#define AS3 __attribute__((address_space(3)))

// ---------------------------------------------------------------------------
// fp32 -> bf16 cast (RNE), 4 elems/thread.
// ---------------------------------------------------------------------------
__global__ __launch_bounds__(256) void cvt_f32_bf16_kernel(
    const float* __restrict__ in, __hip_bfloat16* __restrict__ out, int n4)
{
    const int i = blockIdx.x * 256 + threadIdx.x;
    if (i >= n4) return;
    const float4 v = ((const float4*)in)[i];
    __hip_bfloat16 o[4];
    o[0] = (__hip_bfloat16)v.x; o[1] = (__hip_bfloat16)v.y;
    o[2] = (__hip_bfloat16)v.z; o[3] = (__hip_bfloat16)v.w;
    *(ushort4*)(out + (size_t)i * 4) = *(ushort4*)o;
}

// ---------------------------------------------------------------------------
// Transpose + cast: out[c*R + r] = bf16(in[r*C + c]). 32x32 LDS tiles.
// ---------------------------------------------------------------------------
__global__ __launch_bounds__(256) void transpose_cast_kernel(
    const float* __restrict__ in, __hip_bfloat16* __restrict__ out, int R, int Cc)
{
    __shared__ float tile[32][33];
    const int tr0 = blockIdx.y * 32, tc0 = blockIdx.x * 32;
    const int tx = threadIdx.x & 31, ty = threadIdx.x >> 5;
#pragma unroll
    for (int i = 0; i < 32; i += 8)
        tile[ty + i][tx] = in[(size_t)(tr0 + ty + i) * Cc + tc0 + tx];
    __syncthreads();
#pragma unroll
    for (int i = 0; i < 32; i += 8)
        out[(size_t)(tc0 + ty + i) * R + tr0 + tx] = (__hip_bfloat16)tile[tx][ty + i];
}

// ---------------------------------------------------------------------------
// bfull[i] = bih[i] + dot(Wih[i, E:], b0)
// ---------------------------------------------------------------------------
__global__ __launch_bounds__(256) void bfull_kernel(
    const float* __restrict__ Wih, const float* __restrict__ b0,
    const float* __restrict__ bih, float* __restrict__ bfull)
{
    const int i = blockIdx.x * 256 + threadIdx.x;
    if (i >= 3 * H_) return;
    const float* wrow = Wih + (size_t)i * (E_ + H_) + E_;
    float acc = bih[i];
    for (int j = 0; j < H_; ++j) acc += wrow[j] * b0[j];
    bfull[i] = acc;
}

// ---------------------------------------------------------------------------
// Embedding gather + cast: out[t*B+b, :] = bf16(emb[captions[b,t], :])
// ---------------------------------------------------------------------------
__global__ __launch_bounds__(128) void emb_gather_kernel(
    const int* __restrict__ caps, const float* __restrict__ emb,
    __hip_bfloat16* __restrict__ out)
{
    const int r = blockIdx.x;
    const int t = r >> 8;
    const int b = r & 255;
    const int cap = caps[(size_t)b * T_ + t];
    const int e = threadIdx.x * 4;
    const float4 v = *(const float4*)(emb + (size_t)cap * E_ + e);
    __hip_bfloat16 o[4];
    o[0] = (__hip_bfloat16)v.x; o[1] = (__hip_bfloat16)v.y;
    o[2] = (__hip_bfloat16)v.z; o[3] = (__hip_bfloat16)v.w;
    *(ushort4*)(out + (size_t)r * E_ + e) = *(ushort4*)o;
}

// ---------------------------------------------------------------------------
// 128x128-tile bf16 MFMA GEMM (NT), BK=64, 256 thr = 4 waves (2x2), each wave
// a 64x64 quadrant via 4x4 mfma_f32_16x16x32_bf16. 1D grid with bijective
// XCD swizzle (m204) + rows-fastest chunking for L2 locality.
// M%128==0, Kd%64==0, lda/ldb%8==0; N tail guarded.
// ---------------------------------------------------------------------------
template <typename OutT>
__global__ __launch_bounds__(256) void gemm_bf16_nt128_kernel(
    const __hip_bfloat16* __restrict__ A, const __hip_bfloat16* __restrict__ Bw,
    const float* __restrict__ bias, OutT* __restrict__ C,
    int N, int Kd, int lda, int ldb, int ldc, int nby)
{
    // bijective XCD swizzle: orig -> chunk-per-XCD
    int wg = blockIdx.x;
    {
        const int nwg = gridDim.x;
        const int q = nwg >> 3, r = nwg & 7;
        const int xcd = wg & 7, idx = wg >> 3;
        wg = (xcd < r ? xcd * (q + 1) : r * (q + 1) + (xcd - r) * q) + idx;
    }
    const int by = wg % nby;            // rows fastest within an XCD chunk
    const int bx = wg / nby;
    const int row0 = by * 128;
    const int col0 = bx * 128;

    __shared__ __hip_bfloat16 Asl[128 * 64];
    __shared__ __hip_bfloat16 Bsl[128 * 64];
    const int tid  = threadIdx.x;
    const int lane = tid & 63;
    const int w    = tid >> 6;
    const int wm   = w >> 1, wn = w & 1;

    const int srow = tid >> 3;          // 0..31 per issue
    const int scol = (tid & 7) << 3;    // 0..56

    const int lr = lane & 15;
    const int lk = (lane >> 4) << 3;

    f32x4 acc[4][4] = {};

    const __hip_bfloat16* gA = A + (size_t)(row0 + srow) * lda + scol;
    bool bv[4];
    const __hip_bfloat16* gB[4];
#pragma unroll
    for (int i = 0; i < 4; ++i) {
        const int br = col0 + i * 32 + srow;
        bv[i] = br < N;
        gB[i] = Bw + (size_t)br * ldb + scol;
    }

    for (int k0 = 0; k0 < Kd; k0 += 64) {
        __syncthreads();
#pragma unroll
        for (int i = 0; i < 4; ++i)
            __builtin_amdgcn_global_load_lds((const AS1 void*)(gA + (size_t)i * 32 * lda + k0),
                (AS3 void*)(Asl + i * 2048 + tid * 8), 16, 0, 0);
#pragma unroll
        for (int i = 0; i < 4; ++i)
            if (bv[i]) __builtin_amdgcn_global_load_lds((const AS1 void*)(gB[i] + k0),
                (AS3 void*)(Bsl + i * 2048 + tid * 8), 16, 0, 0);
        __syncthreads();

#pragma unroll
        for (int ks = 0; ks < 2; ++ks) {
            bf16x8 af[4], bfr[4];
#pragma unroll
            for (int i = 0; i < 4; ++i)
                af[i] = *(const bf16x8*)(Asl + (wm * 64 + i * 16 + lr) * 64 + ks * 32 + lk);
#pragma unroll
            for (int j = 0; j < 4; ++j)
                bfr[j] = *(const bf16x8*)(Bsl + (wn * 64 + j * 16 + lr) * 64 + ks * 32 + lk);
#pragma unroll
            for (int i = 0; i < 4; ++i)
#pragma unroll
                for (int j = 0; j < 4; ++j)
                    acc[i][j] = __builtin_amdgcn_mfma_f32_16x16x32_bf16(
                        af[i], bfr[j], acc[i][j], 0, 0, 0);
        }
    }

    const int orow = (lane >> 4) << 2;
#pragma unroll
    for (int i = 0; i < 4; ++i) {
#pragma unroll
        for (int j = 0; j < 4; ++j) {
            const int col = col0 + wn * 64 + j * 16 + lr;
            if (col >= N) continue;
            const float bvv = bias ? bias[col] : 0.f;
            const int rowb = row0 + wm * 64 + i * 16 + orow;
#pragma unroll
            for (int r = 0; r < 4; ++r)
                C[(size_t)(rowb + r) * ldc + col] = (OutT)(acc[i][j][r] + bvv);
        }
    }
}

// ---------------------------------------------------------------------------
// 64x64-tile bf16 MFMA GEMM body (NT) with Cin add (for gigh).
// ---------------------------------------------------------------------------
template <typename OutT>
__device__ __forceinline__ void gemm_nt_body(
    const __hip_bfloat16* __restrict__ A, const __hip_bfloat16* __restrict__ Bw,
    const float* __restrict__ bias, const float* __restrict__ Cin, int ldcin,
    OutT* __restrict__ C, int M, int N, int Kd, int lda, int ldb, int ldc,
    int bx, int by)
{
    __shared__ __hip_bfloat16 Asl[64 * 64];
    __shared__ __hip_bfloat16 Bsl[64 * 64];
    const int tid  = threadIdx.x;
    const int lane = tid & 63;
    const int w    = tid >> 6;
    const int wm   = w >> 1, wn = w & 1;
    const int row0 = by * 64;
    const int col0 = bx * 64;

    const int srow = tid >> 3;
    const int scol = (tid & 7) << 3;

    const int lr = lane & 15;
    const int lk = (lane >> 4) << 3;

    f32x4 acc[2][2] = {};

    const __hip_bfloat16* gA0 = A + (size_t)(row0 + srow) * lda + scol;
    const __hip_bfloat16* gA1 = gA0 + (size_t)32 * lda;
    const int br0 = col0 + srow, br1 = br0 + 32;
    const __hip_bfloat16* gB0 = Bw + (size_t)br0 * ldb + scol;
    const __hip_bfloat16* gB1 = gB0 + (size_t)32 * ldb;
    const bool v0 = br0 < N, v1 = br1 < N;

    for (int k0 = 0; k0 < Kd; k0 += 64) {
        __syncthreads();
        __builtin_amdgcn_global_load_lds((const AS1 void*)(gA0 + k0),
            (AS3 void*)(Asl + tid * 8), 16, 0, 0);
        __builtin_amdgcn_global_load_lds((const AS1 void*)(gA1 + k0),
            (AS3 void*)(Asl + 2048 + tid * 8), 16, 0, 0);
        if (v0) __builtin_amdgcn_global_load_lds((const AS1 void*)(gB0 + k0),
            (AS3 void*)(Bsl + tid * 8), 16, 0, 0);
        if (v1) __builtin_amdgcn_global_load_lds((const AS1 void*)(gB1 + k0),
            (AS3 void*)(Bsl + 2048 + tid * 8), 16, 0, 0);
        __syncthreads();

#pragma unroll
        for (int ks = 0; ks < 2; ++ks) {
            bf16x8 af[2], bfr[2];
#pragma unroll
            for (int i = 0; i < 2; ++i)
                af[i] = *(const bf16x8*)(Asl + (wm * 32 + i * 16 + lr) * 64 + ks * 32 + lk);
#pragma unroll
            for (int j = 0; j < 2; ++j)
                bfr[j] = *(const bf16x8*)(Bsl + (wn * 32 + j * 16 + lr) * 64 + ks * 32 + lk);
#pragma unroll
            for (int i = 0; i < 2; ++i)
#pragma unroll
                for (int j = 0; j < 2; ++j)
                    acc[i][j] = __builtin_amdgcn_mfma_f32_16x16x32_bf16(
                        af[i], bfr[j], acc[i][j], 0, 0, 0);
        }
    }

    const int orow = (lane >> 4) << 2;
#pragma unroll
    for (int i = 0; i < 2; ++i) {
#pragma unroll
        for (int j = 0; j < 2; ++j) {
            const int col = col0 + wn * 32 + j * 16 + lr;
            if (col >= N) continue;
            const float bvv = bias ? bias[col] : 0.f;
            const int rowb = row0 + wm * 32 + i * 16 + orow;
#pragma unroll
            for (int r = 0; r < 4; ++r) {
                float v = acc[i][j][r] + bvv;
                if (Cin) v += Cin[(size_t)(rowb + r) * ldcin + col];
                C[(size_t)(rowb + r) * ldc + col] = (OutT)v;
            }
        }
    }
}

// ---------------------------------------------------------------------------
// Fused gi+gh: z==0: gi = ctx @ Wfused^T + gi_emb_t ; z==1: gh = hb @ Whh^T + bhh
// ---------------------------------------------------------------------------
__global__ __launch_bounds__(256) void gemm_gigh_kernel(
    const __hip_bfloat16* __restrict__ ctx, const __hip_bfloat16* __restrict__ Wf,
    const float* __restrict__ gi_emb_t,
    const __hip_bfloat16* __restrict__ hb, const __hip_bfloat16* __restrict__ Whh,
    const float* __restrict__ bhh,
    float* __restrict__ gi, float* __restrict__ gh)
{
    if (blockIdx.z == 0)
        gemm_nt_body<float>(ctx, Wf, nullptr, gi_emb_t, 3 * H_, gi,
                            B_, 3 * H_, K_, K_, K_, 3 * H_, blockIdx.x, blockIdx.y);
    else
        gemm_nt_body<float>(hb, Whh, bhh, nullptr, 0, gh,
                            B_, 3 * H_, H_, H_, H_, 3 * H_, blockIdx.x, blockIdx.y);
}

// ---------------------------------------------------------------------------
// Fused [GRU(t-1)] + q-projection + additive attention. One block per b.
// tprev >= 0: first apply GRU for row b using gi/gh of step tprev, updating
// h (fp32), hb (bf16), h_all[b*T+tprev]; q then uses the fresh fp32 h.
// ---------------------------------------------------------------------------
__global__ __launch_bounds__(256) void attn_gru_kernel(
    const float* __restrict__ gi, const float* __restrict__ gh,
    float* __restrict__ h, __hip_bfloat16* __restrict__ hb,
    __hip_bfloat16* __restrict__ h_all, int tprev,
    const __hip_bfloat16* __restrict__ WqT, const float* __restrict__ bq,
    const __hip_bfloat16* __restrict__ kp, const __hip_bfloat16* __restrict__ feat,
    const float* __restrict__ Va, const float* __restrict__ bva,
    __hip_bfloat16* __restrict__ ctx)
{
    const int b = blockIdx.x;
    const int tid = threadIdx.x;
    const int lane = tid & 63;
    const int wave = tid >> 6;
    __shared__ float hb_s[H_];
    __shared__ float q_s[H_];
    __shared__ float s_sc[64];
    __shared__ float s_w[64];

    if (tprev >= 0) {
#pragma unroll
        for (int jj = 0; jj < 2; ++jj) {
            const int j = tid + jj * 256;
            const size_t o = (size_t)b * 3 * H_ + j;
            const float ir = gi[o],           hr = gh[o];
            const float iz = gi[o + H_],      hz = gh[o + H_];
            const float in_ = gi[o + 2 * H_], hn = gh[o + 2 * H_];
            const float r = 1.f / (1.f + expf(-(ir + hr)));
            const float z = 1.f / (1.f + expf(-(iz + hz)));
            const float n = tanhf(in_ + r * hn);
            const size_t hi = (size_t)b * H_ + j;
            const float hnew = (1.f - z) * n + z * h[hi];
            h[hi] = hnew;
            hb_s[j] = hnew;
            const __hip_bfloat16 hv = (__hip_bfloat16)hnew;
            hb[hi] = hv;
            h_all[((size_t)b * T_ + tprev) * H_ + j] = hv;
        }
    } else {
        hb_s[tid * 2] = 0.f;
        hb_s[tid * 2 + 1] = 0.f;
    }
    __syncthreads();

    // q[j], j = 2*tid, 2*tid+1  (WqT[k][j] = Wq[j][k]; coalesced row reads)
    {
        float a0 = bq[2 * tid], a1 = bq[2 * tid + 1];
        for (int k = 0; k < H_; ++k) {
            const float hv = hb_s[k];
            const __hip_bfloat16* wr = WqT + (size_t)k * H_ + 2 * tid;
            a0 += hv * (float)wr[0];
            a1 += hv * (float)wr[1];
        }
        q_s[2 * tid] = a0;
        q_s[2 * tid + 1] = a1;
    }
    __syncthreads();

    float qr[8], va[8];
#pragma unroll
    for (int i = 0; i < 8; ++i) {
        qr[i] = q_s[lane * 8 + i];
        va[i] = Va[lane * 8 + i];
    }

    for (int l = wave; l < L_; l += 4) {
        const bf16x8 kv = *(const bf16x8*)(kp + ((size_t)b * L_ + l) * H_ + lane * 8);
        float s = 0.f;
#pragma unroll
        for (int i = 0; i < 8; ++i) s += tanhf(qr[i] + (float)kv[i]) * va[i];
#pragma unroll
        for (int off = 32; off > 0; off >>= 1) s += __shfl_xor(s, off, 64);
        if (lane == 0) s_sc[l] = s + bva[0];
    }
    __syncthreads();

    if (wave == 0) {
        const float v = (lane < L_) ? s_sc[lane] : -1e30f;
        float m = v;
#pragma unroll
        for (int off = 32; off > 0; off >>= 1) m = fmaxf(m, __shfl_xor(m, off, 64));
        const float e = (lane < L_) ? expf(v - m) : 0.f;
        float ssum = e;
#pragma unroll
        for (int off = 32; off > 0; off >>= 1) ssum += __shfl_xor(ssum, off, 64);
        if (lane < L_) s_w[lane] = e / ssum;
    }
    __syncthreads();

#pragma unroll
    for (int r = 0; r < 2; ++r) {
        const int k = tid + r * 256;
        float acc = 0.f;
        const __hip_bfloat16* fb = feat + (size_t)b * L_ * K_ + k;
        for (int l = 0; l < L_; ++l) acc += s_w[l] * (float)fb[(size_t)l * K_];
        ctx[(size_t)b * K_ + k] = (__hip_bfloat16)acc;
    }
}

// ---------------------------------------------------------------------------
// Standalone GRU (final step only).
// ---------------------------------------------------------------------------
__global__ __launch_bounds__(256) void gru_kernel(
    const float* __restrict__ gi, const float* __restrict__ gh,
    float* __restrict__ h, __hip_bfloat16* __restrict__ hb,
    __hip_bfloat16* __restrict__ h_all, int t)
{
    const int idx = blockIdx.x * 256 + threadIdx.x;
    const int b = idx >> 9;
    const int j = idx & (H_ - 1);
    const size_t o = (size_t)b * 3 * H_ + j;
    const float ir = gi[o],           hr = gh[o];
    const float iz = gi[o + H_],      hz = gh[o + H_];
    const float in_ = gi[o + 2 * H_], hn = gh[o + 2 * H_];
    const float r = 1.f / (1.f + expf(-(ir + hr)));
    const float z = 1.f / (1.f + expf(-(iz + hz)));
    const float n = tanhf(in_ + r * hn);
    const float hnew = (1.f - z) * n + z * h[idx];
    h[idx] = hnew;
    const __hip_bfloat16 hv = (__hip_bfloat16)hnew;
    hb[idx] = hv;
    h_all[((size_t)b * T_ + t) * H_ + j] = hv;
}

// ---------------------------------------------------------------------------
extern "C" void kernel_launch(void* const* d_in, const int* in_sizes, int n_in,
                              void* d_out, int out_size, void* d_ws, size_t ws_size,
                              hipStream_t stream)
{
    const float* features = (const float*)d_in[0];
    const int*   captions = (const int*)d_in[1];
    const float* emb  = (const float*)d_in[2];
    const float* Wq   = (const float*)d_in[3];
    const float* bq   = (const float*)d_in[4];
    const float* Uk   = (const float*)d_in[5];
    const float* bk   = (const float*)d_in[6];
    const float* Va   = (const float*)d_in[7];
    const float* bva  = (const float*)d_in[8];
    const float* W0   = (const float*)d_in[9];
    const float* b0   = (const float*)d_in[10];
    const float* Wih  = (const float*)d_in[11];
    const float* bih  = (const float*)d_in[12];
    const float* Whh  = (const float*)d_in[13];
    const float* bhh  = (const float*)d_in[14];
    const float* W1   = (const float*)d_in[15];
    const float* b1   = (const float*)d_in[16];
    float* out = (float*)d_out;

    // fp32 scratch
    float* ws = (float*)d_ws;
    float* h      = ws; ws += B_ * H_;
    float* gi     = ws; ws += B_ * 3 * H_;
    float* gh     = ws; ws += B_ * 3 * H_;
    float* bfull  = ws; ws += 3 * H_;
    float* gi_emb = ws; ws += (size_t)T_ * B_ * 3 * H_;
    // bf16 scratch
    __hip_bfloat16* bws = (__hip_bfloat16*)ws;
    __hip_bfloat16* feat_bf = bws; bws += (size_t)B_ * L_ * K_;
    __hip_bfloat16* kp_bf   = bws; bws += (size_t)B_ * L_ * H_;
    __hip_bfloat16* W1_bf   = bws; bws += (size_t)V_ * H_;
    __hip_bfloat16* Uk_bf   = bws; bws += (size_t)H_ * K_;
    __hip_bfloat16* WqT_bf  = bws; bws += (size_t)H_ * H_;
    __hip_bfloat16* W0T_bf  = bws; bws += (size_t)K_ * H_;
    __hip_bfloat16* Wih_bf  = bws; bws += (size_t)3 * H_ * (E_ + H_);
    __hip_bfloat16* Whh_bf  = bws; bws += (size_t)3 * H_ * H_;
    __hip_bfloat16* Wfused  = bws; bws += (size_t)3 * H_ * K_;
    __hip_bfloat16* emb_all = bws; bws += (size_t)T_ * B_ * E_;
    __hip_bfloat16* hb      = bws; bws += (size_t)B_ * H_;
    __hip_bfloat16* ctx_bf  = bws; bws += (size_t)B_ * K_;
    __hip_bfloat16* h_all   = bws; bws += (size_t)B_ * T_ * H_;

    hipMemsetAsync(h, 0, (size_t)B_ * H_ * sizeof(float), stream);
    hipMemsetAsync(hb, 0, (size_t)B_ * H_ * sizeof(__hip_bfloat16), stream);

    const dim3 blk(256);
    auto cvt = [&](const float* src, __hip_bfloat16* dst, size_t n) {
        const int n4 = (int)(n / 4);
        cvt_f32_bf16_kernel<<<dim3((n4 + 255) / 256), blk, 0, stream>>>(src, dst, n4);
    };

    // ---- prologue ----
    cvt(features, feat_bf, (size_t)B_ * L_ * K_);
    cvt(W1, W1_bf, (size_t)V_ * H_);
    cvt(Uk, Uk_bf, (size_t)H_ * K_);
    cvt(Wih, Wih_bf, (size_t)3 * H_ * (E_ + H_));
    cvt(Whh, Whh_bf, (size_t)3 * H_ * H_);
    transpose_cast_kernel<<<dim3(H_ / 32, H_ / 32), blk, 0, stream>>>(Wq, WqT_bf, H_, H_);
    transpose_cast_kernel<<<dim3(K_ / 32, H_ / 32), blk, 0, stream>>>(W0, W0T_bf, H_, K_);
    bfull_kernel<<<dim3((3 * H_ + 255) / 256), blk, 0, stream>>>(Wih, b0, bih, bfull);
    emb_gather_kernel<<<dim3(T_ * B_), dim3(128), 0, stream>>>(captions, emb, emb_all);

    // keys_proj = features @ Uk^T + bk -> bf16 [B*L, H]   (98x4 = 392 tiles)
    gemm_bf16_nt128_kernel<__hip_bfloat16><<<dim3((B_ * L_ / 128) * (H_ / 128)), blk, 0, stream>>>(
        feat_bf, Uk_bf, bk, kp_bf, H_, K_, K_, K_, H_, B_ * L_ / 128);

    // Wfused[3H, K] = Wih[:, E:] @ W0   (12x4 = 48 tiles)
    gemm_bf16_nt128_kernel<__hip_bfloat16><<<dim3((3 * H_ / 128) * (K_ / 128)), blk, 0, stream>>>(
        Wih_bf + E_, W0T_bf, nullptr, Wfused, K_, H_, E_ + H_, H_, K_, 3 * H_ / 128);

    // gi_emb[t*B+b, :] = emb_t @ WihE^T + (bih + WihE@b0)   (30x12 = 360 tiles)
    gemm_bf16_nt128_kernel<float><<<dim3((T_ * B_ / 128) * (3 * H_ / 128)), blk, 0, stream>>>(
        emb_all, Wih_bf, bfull, gi_emb, 3 * H_, E_, E_, E_ + H_, 3 * H_, T_ * B_ / 128);

    // ---- recurrence: 2 dispatches per step ----
    for (int t = 0; t < T_; ++t) {
        attn_gru_kernel<<<dim3(B_), blk, 0, stream>>>(
            gi, gh, h, hb, h_all, t - 1,
            WqT_bf, bq, kp_bf, feat_bf, Va, bva, ctx_bf);
        gemm_gigh_kernel<<<dim3(3 * H_ / 64, B_ / 64, 2), blk, 0, stream>>>(
            ctx_bf, Wfused, gi_emb + (size_t)t * B_ * 3 * H_,
            hb, Whh_bf, bhh, gi, gh);
    }
    // final GRU (t = T-1)
    gru_kernel<<<dim3(B_ * H_ / 256), blk, 0, stream>>>(gi, gh, h, hb, h_all, T_ - 1);

    // ---- epilogue: out[b*T+t, :] = h_all @ W1^T + b1   (30x79 = 2370 tiles)
    gemm_bf16_nt128_kernel<float><<<dim3((B_ * T_ / 128) * ((V_ + 127) / 128)), blk, 0, stream>>>(
        h_all, W1_bf, b1, out, V_, H_, H_, H_, V_, B_ * T_ / 128);
}

// Round 9
// 785.083 us; speedup vs baseline: 4.7269x; 1.2818x over previous
//
#include <hip/hip_runtime.h>
#include <hip/hip_bf16.h>
#include <math.h>

#define B_ 256
#define L_ 49
#define V_ 10000
#define E_ 512
#define H_ 512
#define K_ 512
#define T_ 15

typedef __bf16 bf16x8 __attribute__((ext_vector_type(8)));
typedef float f32x4 __attribute__((ext_vector_type(4)));

#define AS1 __attribute__((address_space(1)))
#define AS3 __attribute__((address_space(3)))

__device__ __forceinline__ float tanh_fast(float x)
{
    const float ax = fabsf(x);
    const float e = __expf(2.f * ax);
    const float t = 1.f - 2.f / (e + 1.f);
    return copysignf(t, x);
}

// ---------------------------------------------------------------------------
// fp32 -> bf16 cast (RNE), 4 elems/thread.
// ---------------------------------------------------------------------------
__global__ __launch_bounds__(256) void cvt_f32_bf16_kernel(
    const float* __restrict__ in, __hip_bfloat16* __restrict__ out, int n4)
{
    const int i = blockIdx.x * 256 + threadIdx.x;
    if (i >= n4) return;
    const float4 v = ((const float4*)in)[i];
    __hip_bfloat16 o[4];
    o[0] = (__hip_bfloat16)v.x; o[1] = (__hip_bfloat16)v.y;
    o[2] = (__hip_bfloat16)v.z; o[3] = (__hip_bfloat16)v.w;
    *(ushort4*)(out + (size_t)i * 4) = *(ushort4*)o;
}

// ---------------------------------------------------------------------------
// Transpose + cast: out[c*R + r] = bf16(in[r*C + c]). 32x32 LDS tiles.
// ---------------------------------------------------------------------------
__global__ __launch_bounds__(256) void transpose_cast_kernel(
    const float* __restrict__ in, __hip_bfloat16* __restrict__ out, int R, int Cc)
{
    __shared__ float tile[32][33];
    const int tr0 = blockIdx.y * 32, tc0 = blockIdx.x * 32;
    const int tx = threadIdx.x & 31, ty = threadIdx.x >> 5;
#pragma unroll
    for (int i = 0; i < 32; i += 8)
        tile[ty + i][tx] = in[(size_t)(tr0 + ty + i) * Cc + tc0 + tx];
    __syncthreads();
#pragma unroll
    for (int i = 0; i < 32; i += 8)
        out[(size_t)(tc0 + ty + i) * R + tr0 + tx] = (__hip_bfloat16)tile[tx][ty + i];
}

// ---------------------------------------------------------------------------
// bfull[i] = bih[i] + dot(Wih[i, E:], b0)
// ---------------------------------------------------------------------------
__global__ __launch_bounds__(256) void bfull_kernel(
    const float* __restrict__ Wih, const float* __restrict__ b0,
    const float* __restrict__ bih, float* __restrict__ bfull)
{
    const int i = blockIdx.x * 256 + threadIdx.x;
    if (i >= 3 * H_) return;
    const float* wrow = Wih + (size_t)i * (E_ + H_) + E_;
    float acc = bih[i];
    for (int j = 0; j < H_; ++j) acc += wrow[j] * b0[j];
    bfull[i] = acc;
}

// ---------------------------------------------------------------------------
// Embedding gather + cast: out[t*B+b, :] = bf16(emb[captions[b,t], :])
// ---------------------------------------------------------------------------
__global__ __launch_bounds__(128) void emb_gather_kernel(
    const int* __restrict__ caps, const float* __restrict__ emb,
    __hip_bfloat16* __restrict__ out)
{
    const int r = blockIdx.x;
    const int t = r >> 8;
    const int b = r & 255;
    const int cap = caps[(size_t)b * T_ + t];
    const int e = threadIdx.x * 4;
    const float4 v = *(const float4*)(emb + (size_t)cap * E_ + e);
    __hip_bfloat16 o[4];
    o[0] = (__hip_bfloat16)v.x; o[1] = (__hip_bfloat16)v.y;
    o[2] = (__hip_bfloat16)v.z; o[3] = (__hip_bfloat16)v.w;
    *(ushort4*)(out + (size_t)r * E_ + e) = *(ushort4*)o;
}

// ---------------------------------------------------------------------------
// 128x128-tile bf16 MFMA GEMM (NT), BK=64, XCD-swizzled 1D grid (m204).
// ---------------------------------------------------------------------------
template <typename OutT>
__global__ __launch_bounds__(256) void gemm_bf16_nt128_kernel(
    const __hip_bfloat16* __restrict__ A, const __hip_bfloat16* __restrict__ Bw,
    const float* __restrict__ bias, OutT* __restrict__ C,
    int N, int Kd, int lda, int ldb, int ldc, int nby)
{
    int wg = blockIdx.x;
    {
        const int nwg = gridDim.x;
        const int q = nwg >> 3, r = nwg & 7;
        const int xcd = wg & 7, idx = wg >> 3;
        wg = (xcd < r ? xcd * (q + 1) : r * (q + 1) + (xcd - r) * q) + idx;
    }
    const int by = wg % nby;
    const int bx = wg / nby;
    const int row0 = by * 128;
    const int col0 = bx * 128;

    __shared__ __hip_bfloat16 Asl[128 * 64];
    __shared__ __hip_bfloat16 Bsl[128 * 64];
    const int tid  = threadIdx.x;
    const int lane = tid & 63;
    const int w    = tid >> 6;
    const int wm   = w >> 1, wn = w & 1;

    const int srow = tid >> 3;
    const int scol = (tid & 7) << 3;

    const int lr = lane & 15;
    const int lk = (lane >> 4) << 3;

    f32x4 acc[4][4] = {};

    const __hip_bfloat16* gA = A + (size_t)(row0 + srow) * lda + scol;
    bool bv[4];
    const __hip_bfloat16* gB[4];
#pragma unroll
    for (int i = 0; i < 4; ++i) {
        const int br = col0 + i * 32 + srow;
        bv[i] = br < N;
        gB[i] = Bw + (size_t)br * ldb + scol;
    }

    for (int k0 = 0; k0 < Kd; k0 += 64) {
        __syncthreads();
#pragma unroll
        for (int i = 0; i < 4; ++i)
            __builtin_amdgcn_global_load_lds((const AS1 void*)(gA + (size_t)i * 32 * lda + k0),
                (AS3 void*)(Asl + i * 2048 + tid * 8), 16, 0, 0);
#pragma unroll
        for (int i = 0; i < 4; ++i)
            if (bv[i]) __builtin_amdgcn_global_load_lds((const AS1 void*)(gB[i] + k0),
                (AS3 void*)(Bsl + i * 2048 + tid * 8), 16, 0, 0);
        __syncthreads();

#pragma unroll
        for (int ks = 0; ks < 2; ++ks) {
            bf16x8 af[4], bfr[4];
#pragma unroll
            for (int i = 0; i < 4; ++i)
                af[i] = *(const bf16x8*)(Asl + (wm * 64 + i * 16 + lr) * 64 + ks * 32 + lk);
#pragma unroll
            for (int j = 0; j < 4; ++j)
                bfr[j] = *(const bf16x8*)(Bsl + (wn * 64 + j * 16 + lr) * 64 + ks * 32 + lk);
#pragma unroll
            for (int i = 0; i < 4; ++i)
#pragma unroll
                for (int j = 0; j < 4; ++j)
                    acc[i][j] = __builtin_amdgcn_mfma_f32_16x16x32_bf16(
                        af[i], bfr[j], acc[i][j], 0, 0, 0);
        }
    }

    const int orow = (lane >> 4) << 2;
#pragma unroll
    for (int i = 0; i < 4; ++i) {
#pragma unroll
        for (int j = 0; j < 4; ++j) {
            const int col = col0 + wn * 64 + j * 16 + lr;
            if (col >= N) continue;
            const float bvv = bias ? bias[col] : 0.f;
            const int rowb = row0 + wm * 64 + i * 16 + orow;
#pragma unroll
            for (int r = 0; r < 4; ++r)
                C[(size_t)(rowb + r) * ldc + col] = (OutT)(acc[i][j][r] + bvv);
        }
    }
}

// ---------------------------------------------------------------------------
// 64x64-tile bf16 MFMA GEMM body (NT), BK=128 (4 K-iters at K=512), Cin add.
// M,N,K multiples as used by gigh (M=256, N=1536, K=512).
// ---------------------------------------------------------------------------
template <typename OutT>
__device__ __forceinline__ void gemm_nt_body(
    const __hip_bfloat16* __restrict__ A, const __hip_bfloat16* __restrict__ Bw,
    const float* __restrict__ bias, const float* __restrict__ Cin, int ldcin,
    OutT* __restrict__ C, int M, int N, int Kd, int lda, int ldb, int ldc,
    int bx, int by)
{
    __shared__ __hip_bfloat16 Asl[64 * 128];
    __shared__ __hip_bfloat16 Bsl[64 * 128];
    const int tid  = threadIdx.x;
    const int lane = tid & 63;
    const int w    = tid >> 6;
    const int wm   = w >> 1, wn = w & 1;
    const int row0 = by * 64;
    const int col0 = bx * 64;

    const int srow = tid >> 4;           // 0..15
    const int scol = (tid & 15) << 3;    // 0..120

    const int lr = lane & 15;
    const int lk = (lane >> 4) << 3;

    f32x4 acc[2][2] = {};

    const __hip_bfloat16* gA = A + (size_t)(row0 + srow) * lda + scol;
    const __hip_bfloat16* gB = Bw + (size_t)(col0 + srow) * ldb + scol;

    for (int k0 = 0; k0 < Kd; k0 += 128) {
        __syncthreads();
#pragma unroll
        for (int i = 0; i < 4; ++i)
            __builtin_amdgcn_global_load_lds((const AS1 void*)(gA + (size_t)(i * 16) * lda + k0),
                (AS3 void*)(Asl + i * 2048 + tid * 8), 16, 0, 0);
#pragma unroll
        for (int i = 0; i < 4; ++i)
            __builtin_amdgcn_global_load_lds((const AS1 void*)(gB + (size_t)(i * 16) * ldb + k0),
                (AS3 void*)(Bsl + i * 2048 + tid * 8), 16, 0, 0);
        __syncthreads();

#pragma unroll
        for (int ks = 0; ks < 4; ++ks) {
            bf16x8 af[2], bfr[2];
#pragma unroll
            for (int i = 0; i < 2; ++i)
                af[i] = *(const bf16x8*)(Asl + (wm * 32 + i * 16 + lr) * 128 + ks * 32 + lk);
#pragma unroll
            for (int j = 0; j < 2; ++j)
                bfr[j] = *(const bf16x8*)(Bsl + (wn * 32 + j * 16 + lr) * 128 + ks * 32 + lk);
#pragma unroll
            for (int i = 0; i < 2; ++i)
#pragma unroll
                for (int j = 0; j < 2; ++j)
                    acc[i][j] = __builtin_amdgcn_mfma_f32_16x16x32_bf16(
                        af[i], bfr[j], acc[i][j], 0, 0, 0);
        }
    }

    const int orow = (lane >> 4) << 2;
#pragma unroll
    for (int i = 0; i < 2; ++i) {
#pragma unroll
        for (int j = 0; j < 2; ++j) {
            const int col = col0 + wn * 32 + j * 16 + lr;
            if (col >= N) continue;
            const float bvv = bias ? bias[col] : 0.f;
            const int rowb = row0 + wm * 32 + i * 16 + orow;
#pragma unroll
            for (int r = 0; r < 4; ++r) {
                float v = acc[i][j][r] + bvv;
                if (Cin) v += Cin[(size_t)(rowb + r) * ldcin + col];
                C[(size_t)(rowb + r) * ldc + col] = (OutT)v;
            }
        }
    }
}

// ---------------------------------------------------------------------------
// Fused gi+gh: z==0: gi = ctx @ Wfused^T + gi_emb_t ; z==1: gh = hb @ Whh^T + bhh
// grid (24, 4, 2)
// ---------------------------------------------------------------------------
__global__ __launch_bounds__(256) void gemm_gigh_kernel(
    const __hip_bfloat16* __restrict__ ctx, const __hip_bfloat16* __restrict__ Wf,
    const float* __restrict__ gi_emb_t,
    const __hip_bfloat16* __restrict__ hb, const __hip_bfloat16* __restrict__ Whh,
    const float* __restrict__ bhh,
    float* __restrict__ gi, float* __restrict__ gh)
{
    if (blockIdx.z == 0)
        gemm_nt_body<float>(ctx, Wf, nullptr, gi_emb_t, 3 * H_, gi,
                            B_, 3 * H_, K_, K_, K_, 3 * H_, blockIdx.x, blockIdx.y);
    else
        gemm_nt_body<float>(hb, Whh, bhh, nullptr, 0, gh,
                            B_, 3 * H_, H_, H_, H_, 3 * H_, blockIdx.x, blockIdx.y);
}

// ---------------------------------------------------------------------------
// Fused [GRU(t-1)] + q-projection + additive attention. One block per b.
// q-projection: 4-wave split-K, lane owns 8 output cols (bf16x8 weight loads),
// partials reduced through LDS.
// ---------------------------------------------------------------------------
__global__ __launch_bounds__(256) void attn_gru_kernel(
    const float* __restrict__ gi, const float* __restrict__ gh,
    float* __restrict__ h, __hip_bfloat16* __restrict__ hb,
    __hip_bfloat16* __restrict__ h_all, int tprev,
    const __hip_bfloat16* __restrict__ WqT, const float* __restrict__ bq,
    const __hip_bfloat16* __restrict__ kp, const __hip_bfloat16* __restrict__ feat,
    const float* __restrict__ Va, const float* __restrict__ bva,
    __hip_bfloat16* __restrict__ ctx)
{
    const int b = blockIdx.x;
    const int tid = threadIdx.x;
    const int lane = tid & 63;
    const int wave = tid >> 6;
    __shared__ float hb_s[H_];
    __shared__ float q_part[4][H_];
    __shared__ float q_s[H_];
    __shared__ float s_sc[64];
    __shared__ float s_w[64];

    if (tprev >= 0) {
#pragma unroll
        for (int jj = 0; jj < 2; ++jj) {
            const int j = tid + jj * 256;
            const size_t o = (size_t)b * (3 * H_) + j;
            const float ir = gi[o],           hr = gh[o];
            const float iz = gi[o + H_],      hz = gh[o + H_];
            const float in_ = gi[o + 2 * H_], hn = gh[o + 2 * H_];
            const float rr = 1.f / (1.f + expf(-(ir + hr)));
            const float zz = 1.f / (1.f + expf(-(iz + hz)));
            const float nn = tanhf(in_ + rr * hn);
            const size_t hi = (size_t)b * H_ + j;
            const float hnew = (1.f - zz) * nn + zz * h[hi];
            h[hi] = hnew;
            hb_s[j] = hnew;
            const __hip_bfloat16 hv = (__hip_bfloat16)hnew;
            hb[hi] = hv;
            h_all[((size_t)b * T_ + tprev) * H_ + j] = hv;
        }
    } else {
        hb_s[tid * 2] = 0.f;
        hb_s[tid * 2 + 1] = 0.f;
    }
    __syncthreads();

    // q = h @ Wq^T + bq : wave w covers k in [w*128,(w+1)*128), lane owns
    // cols [lane*8, lane*8+8). WqT[k][j] = Wq[j][k] -> coalesced bf16x8 loads.
    {
        const int j0 = lane * 8;
        float accq[8] = {};
        const __hip_bfloat16* wbase = WqT + (size_t)wave * 128 * H_ + j0;
#pragma unroll 4
        for (int k = 0; k < 128; ++k) {
            const float hv = hb_s[wave * 128 + k];
            const bf16x8 wv = *(const bf16x8*)(wbase + (size_t)k * H_);
#pragma unroll
            for (int i = 0; i < 8; ++i) accq[i] = fmaf(hv, (float)wv[i], accq[i]);
        }
#pragma unroll
        for (int i = 0; i < 8; ++i) q_part[wave][j0 + i] = accq[i];
    }
    __syncthreads();
    {
        const int j = tid * 2;
        q_s[j]     = bq[j]     + q_part[0][j]     + q_part[1][j]     + q_part[2][j]     + q_part[3][j];
        q_s[j + 1] = bq[j + 1] + q_part[0][j + 1] + q_part[1][j + 1] + q_part[2][j + 1] + q_part[3][j + 1];
    }
    __syncthreads();

    float qr[8], va[8];
#pragma unroll
    for (int i = 0; i < 8; ++i) {
        qr[i] = q_s[lane * 8 + i];
        va[i] = Va[lane * 8 + i];
    }

    for (int l = wave; l < L_; l += 4) {
        const bf16x8 kv = *(const bf16x8*)(kp + ((size_t)b * L_ + l) * H_ + lane * 8);
        float s = 0.f;
#pragma unroll
        for (int i = 0; i < 8; ++i) s += tanh_fast(qr[i] + (float)kv[i]) * va[i];
#pragma unroll
        for (int off = 32; off > 0; off >>= 1) s += __shfl_xor(s, off, 64);
        if (lane == 0) s_sc[l] = s + bva[0];
    }
    __syncthreads();

    if (wave == 0) {
        const float v = (lane < L_) ? s_sc[lane] : -1e30f;
        float m = v;
#pragma unroll
        for (int off = 32; off > 0; off >>= 1) m = fmaxf(m, __shfl_xor(m, off, 64));
        const float e = (lane < L_) ? expf(v - m) : 0.f;
        float ssum = e;
#pragma unroll
        for (int off = 32; off > 0; off >>= 1) ssum += __shfl_xor(ssum, off, 64);
        if (lane < L_) s_w[lane] = e / ssum;
    }
    __syncthreads();

    // ctx: both k-chunks in one l-loop (2 accumulators for load pipelining)
    {
        float acc0 = 0.f, acc1 = 0.f;
        const __hip_bfloat16* fb = feat + (size_t)b * L_ * K_;
#pragma unroll 7
        for (int l = 0; l < L_; ++l) {
            const float wl = s_w[l];
            acc0 = fmaf(wl, (float)fb[(size_t)l * K_ + tid], acc0);
            acc1 = fmaf(wl, (float)fb[(size_t)l * K_ + tid + 256], acc1);
        }
        ctx[(size_t)b * K_ + tid]       = (__hip_bfloat16)acc0;
        ctx[(size_t)b * K_ + tid + 256] = (__hip_bfloat16)acc1;
    }
}

// ---------------------------------------------------------------------------
// Standalone GRU (final step only).
// ---------------------------------------------------------------------------
__global__ __launch_bounds__(256) void gru_kernel(
    const float* __restrict__ gi, const float* __restrict__ gh,
    float* __restrict__ h, __hip_bfloat16* __restrict__ hb,
    __hip_bfloat16* __restrict__ h_all, int t)
{
    const int idx = blockIdx.x * 256 + threadIdx.x;
    const int b = idx >> 9;
    const int j = idx & (H_ - 1);
    const size_t o = (size_t)b * 3 * H_ + j;
    const float ir = gi[o],           hr = gh[o];
    const float iz = gi[o + H_],      hz = gh[o + H_];
    const float in_ = gi[o + 2 * H_], hn = gh[o + 2 * H_];
    const float r = 1.f / (1.f + expf(-(ir + hr)));
    const float z = 1.f / (1.f + expf(-(iz + hz)));
    const float n = tanhf(in_ + r * hn);
    const float hnew = (1.f - z) * n + z * h[idx];
    h[idx] = hnew;
    const __hip_bfloat16 hv = (__hip_bfloat16)hnew;
    hb[idx] = hv;
    h_all[((size_t)b * T_ + t) * H_ + j] = hv;
}

// ---------------------------------------------------------------------------
extern "C" void kernel_launch(void* const* d_in, const int* in_sizes, int n_in,
                              void* d_out, int out_size, void* d_ws, size_t ws_size,
                              hipStream_t stream)
{
    const float* features = (const float*)d_in[0];
    const int*   captions = (const int*)d_in[1];
    const float* emb  = (const float*)d_in[2];
    const float* Wq   = (const float*)d_in[3];
    const float* bq   = (const float*)d_in[4];
    const float* Uk   = (const float*)d_in[5];
    const float* bk   = (const float*)d_in[6];
    const float* Va   = (const float*)d_in[7];
    const float* bva  = (const float*)d_in[8];
    const float* W0   = (const float*)d_in[9];
    const float* b0   = (const float*)d_in[10];
    const float* Wih  = (const float*)d_in[11];
    const float* bih  = (const float*)d_in[12];
    const float* Whh  = (const float*)d_in[13];
    const float* bhh  = (const float*)d_in[14];
    const float* W1   = (const float*)d_in[15];
    const float* b1   = (const float*)d_in[16];
    float* out = (float*)d_out;

    // fp32 scratch
    float* ws = (float*)d_ws;
    float* h      = ws; ws += B_ * H_;
    float* gi     = ws; ws += B_ * 3 * H_;
    float* gh     = ws; ws += B_ * 3 * H_;
    float* bfull  = ws; ws += 3 * H_;
    float* gi_emb = ws; ws += (size_t)T_ * B_ * 3 * H_;
    // bf16 scratch
    __hip_bfloat16* bws = (__hip_bfloat16*)ws;
    __hip_bfloat16* feat_bf = bws; bws += (size_t)B_ * L_ * K_;
    __hip_bfloat16* kp_bf   = bws; bws += (size_t)B_ * L_ * H_;
    __hip_bfloat16* W1_bf   = bws; bws += (size_t)V_ * H_;
    __hip_bfloat16* Uk_bf   = bws; bws += (size_t)H_ * K_;
    __hip_bfloat16* WqT_bf  = bws; bws += (size_t)H_ * H_;
    __hip_bfloat16* W0T_bf  = bws; bws += (size_t)K_ * H_;
    __hip_bfloat16* Wih_bf  = bws; bws += (size_t)3 * H_ * (E_ + H_);
    __hip_bfloat16* Whh_bf  = bws; bws += (size_t)3 * H_ * H_;
    __hip_bfloat16* Wfused  = bws; bws += (size_t)3 * H_ * K_;
    __hip_bfloat16* emb_all = bws; bws += (size_t)T_ * B_ * E_;
    __hip_bfloat16* hb      = bws; bws += (size_t)B_ * H_;
    __hip_bfloat16* ctx_bf  = bws; bws += (size_t)B_ * K_;
    __hip_bfloat16* h_all   = bws; bws += (size_t)B_ * T_ * H_;

    hipMemsetAsync(h, 0, (size_t)B_ * H_ * sizeof(float), stream);
    hipMemsetAsync(hb, 0, (size_t)B_ * H_ * sizeof(__hip_bfloat16), stream);

    const dim3 blk(256);
    auto cvt = [&](const float* src, __hip_bfloat16* dst, size_t n) {
        const int n4 = (int)(n / 4);
        cvt_f32_bf16_kernel<<<dim3((n4 + 255) / 256), blk, 0, stream>>>(src, dst, n4);
    };

    // ---- prologue ----
    cvt(features, feat_bf, (size_t)B_ * L_ * K_);
    cvt(W1, W1_bf, (size_t)V_ * H_);
    cvt(Uk, Uk_bf, (size_t)H_ * K_);
    cvt(Wih, Wih_bf, (size_t)3 * H_ * (E_ + H_));
    cvt(Whh, Whh_bf, (size_t)3 * H_ * H_);
    transpose_cast_kernel<<<dim3(H_ / 32, H_ / 32), blk, 0, stream>>>(Wq, WqT_bf, H_, H_);
    transpose_cast_kernel<<<dim3(K_ / 32, H_ / 32), blk, 0, stream>>>(W0, W0T_bf, H_, K_);
    bfull_kernel<<<dim3((3 * H_ + 255) / 256), blk, 0, stream>>>(Wih, b0, bih, bfull);
    emb_gather_kernel<<<dim3(T_ * B_), dim3(128), 0, stream>>>(captions, emb, emb_all);

    // keys_proj = features @ Uk^T + bk -> bf16 [B*L, H]
    gemm_bf16_nt128_kernel<__hip_bfloat16><<<dim3((B_ * L_ / 128) * (H_ / 128)), blk, 0, stream>>>(
        feat_bf, Uk_bf, bk, kp_bf, H_, K_, K_, K_, H_, B_ * L_ / 128);

    // Wfused[3H, K] = Wih[:, E:] @ W0
    gemm_bf16_nt128_kernel<__hip_bfloat16><<<dim3((3 * H_ / 128) * (K_ / 128)), blk, 0, stream>>>(
        Wih_bf + E_, W0T_bf, nullptr, Wfused, K_, H_, E_ + H_, H_, K_, 3 * H_ / 128);

    // gi_emb[t*B+b, :] = emb_t @ WihE^T + (bih + WihE@b0)
    gemm_bf16_nt128_kernel<float><<<dim3((T_ * B_ / 128) * (3 * H_ / 128)), blk, 0, stream>>>(
        emb_all, Wih_bf, bfull, gi_emb, 3 * H_, E_, E_, E_ + H_, 3 * H_, T_ * B_ / 128);

    // ---- recurrence: 2 dispatches per step ----
    for (int t = 0; t < T_; ++t) {
        attn_gru_kernel<<<dim3(B_), blk, 0, stream>>>(
            gi, gh, h, hb, h_all, t - 1,
            WqT_bf, bq, kp_bf, feat_bf, Va, bva, ctx_bf);
        gemm_gigh_kernel<<<dim3(3 * H_ / 64, B_ / 64, 2), blk, 0, stream>>>(
            ctx_bf, Wfused, gi_emb + (size_t)t * B_ * 3 * H_,
            hb, Whh_bf, bhh, gi, gh);
    }
    // final GRU (t = T-1)
    gru_kernel<<<dim3(B_ * H_ / 256), blk, 0, stream>>>(gi, gh, h, hb, h_all, T_ - 1);

    // ---- epilogue: out[b*T+t, :] = h_all @ W1^T + b1 ----
    gemm_bf16_nt128_kernel<float><<<dim3((B_ * T_ / 128) * ((V_ + 127) / 128)), blk, 0, stream>>>(
        h_all, W1_bf, b1, out, V_, H_, H_, H_, V_, B_ * T_ / 128);
}

// Round 10
// 781.386 us; speedup vs baseline: 4.7492x; 1.0047x over previous
//
#include <hip/hip_runtime.h>
#include <hip/hip_bf16.h>
#include <math.h>

#define B_ 256
#define L_ 49
#define V_ 10000
#define E_ 512
#define H_ 512
#define K_ 512
#define T_ 15

typedef __bf16 bf16x8 __attribute__((ext_vector_type(8)));
typedef float f32x4 __attribute__((ext_vector_type(4)));

#define AS1 __attribute__((address_space(1)))
#define AS3 __attribute__((address_space(3)))

__device__ __forceinline__ float tanh_fast(float x)
{
    const float ax = fabsf(x);
    const float e = __expf(2.f * ax);
    const float t = 1.f - 2.f / (e + 1.f);
    return copysignf(t, x);
}

// ---------------------------------------------------------------------------
// Merged fp32 -> bf16 casts: 5 segments, each n4 % 256 == 0 (verified host-side).
// ---------------------------------------------------------------------------
struct CvtSegs {
    const float* src[5];
    __hip_bfloat16* dst[5];
    int blk_end[5];
};

__global__ __launch_bounds__(256) void cvt_multi_kernel(CvtSegs s)
{
    const int blk = blockIdx.x;
    int seg = 0;
    while (blk >= s.blk_end[seg]) ++seg;
    const int base = seg ? s.blk_end[seg - 1] : 0;
    const int i = (blk - base) * 256 + threadIdx.x;
    const float4 v = ((const float4*)s.src[seg])[i];
    __hip_bfloat16 o[4];
    o[0] = (__hip_bfloat16)v.x; o[1] = (__hip_bfloat16)v.y;
    o[2] = (__hip_bfloat16)v.z; o[3] = (__hip_bfloat16)v.w;
    *(ushort4*)(s.dst[seg] + (size_t)i * 4) = *(ushort4*)o;
}

// ---------------------------------------------------------------------------
// Transpose + cast: out[c*R + r] = bf16(in[r*C + c]). 32x32 LDS tiles.
// ---------------------------------------------------------------------------
__global__ __launch_bounds__(256) void transpose_cast_kernel(
    const float* __restrict__ in, __hip_bfloat16* __restrict__ out, int R, int Cc)
{
    __shared__ float tile[32][33];
    const int tr0 = blockIdx.y * 32, tc0 = blockIdx.x * 32;
    const int tx = threadIdx.x & 31, ty = threadIdx.x >> 5;
#pragma unroll
    for (int i = 0; i < 32; i += 8)
        tile[ty + i][tx] = in[(size_t)(tr0 + ty + i) * Cc + tc0 + tx];
    __syncthreads();
#pragma unroll
    for (int i = 0; i < 32; i += 8)
        out[(size_t)(tc0 + ty + i) * R + tr0 + tx] = (__hip_bfloat16)tile[tx][ty + i];
}

// ---------------------------------------------------------------------------
// bfull[i] = bih[i] + dot(Wih[i, E:], b0)
// ---------------------------------------------------------------------------
__global__ __launch_bounds__(256) void bfull_kernel(
    const float* __restrict__ Wih, const float* __restrict__ b0,
    const float* __restrict__ bih, float* __restrict__ bfull)
{
    const int i = blockIdx.x * 256 + threadIdx.x;
    if (i >= 3 * H_) return;
    const float* wrow = Wih + (size_t)i * (E_ + H_) + E_;
    float acc = bih[i];
    for (int j = 0; j < H_; ++j) acc += wrow[j] * b0[j];
    bfull[i] = acc;
}

// ---------------------------------------------------------------------------
// Embedding gather + cast: out[t*B+b, :] = bf16(emb[captions[b,t], :])
// ---------------------------------------------------------------------------
__global__ __launch_bounds__(128) void emb_gather_kernel(
    const int* __restrict__ caps, const float* __restrict__ emb,
    __hip_bfloat16* __restrict__ out)
{
    const int r = blockIdx.x;
    const int t = r >> 8;
    const int b = r & 255;
    const int cap = caps[(size_t)b * T_ + t];
    const int e = threadIdx.x * 4;
    const float4 v = *(const float4*)(emb + (size_t)cap * E_ + e);
    __hip_bfloat16 o[4];
    o[0] = (__hip_bfloat16)v.x; o[1] = (__hip_bfloat16)v.y;
    o[2] = (__hip_bfloat16)v.z; o[3] = (__hip_bfloat16)v.w;
    *(ushort4*)(out + (size_t)r * E_ + e) = *(ushort4*)o;
}

// ---------------------------------------------------------------------------
// 128x128-tile bf16 MFMA GEMM (NT), BK=64, XCD-swizzled 1D grid (m204).
// ---------------------------------------------------------------------------
template <typename OutT>
__global__ __launch_bounds__(256) void gemm_bf16_nt128_kernel(
    const __hip_bfloat16* __restrict__ A, const __hip_bfloat16* __restrict__ Bw,
    const float* __restrict__ bias, OutT* __restrict__ C,
    int N, int Kd, int lda, int ldb, int ldc, int nby)
{
    int wg = blockIdx.x;
    {
        const int nwg = gridDim.x;
        const int q = nwg >> 3, r = nwg & 7;
        const int xcd = wg & 7, idx = wg >> 3;
        wg = (xcd < r ? xcd * (q + 1) : r * (q + 1) + (xcd - r) * q) + idx;
    }
    const int by = wg % nby;
    const int bx = wg / nby;
    const int row0 = by * 128;
    const int col0 = bx * 128;

    __shared__ __hip_bfloat16 Asl[128 * 64];
    __shared__ __hip_bfloat16 Bsl[128 * 64];
    const int tid  = threadIdx.x;
    const int lane = tid & 63;
    const int w    = tid >> 6;
    const int wm   = w >> 1, wn = w & 1;

    const int srow = tid >> 3;
    const int scol = (tid & 7) << 3;

    const int lr = lane & 15;
    const int lk = (lane >> 4) << 3;

    f32x4 acc[4][4] = {};

    const __hip_bfloat16* gA = A + (size_t)(row0 + srow) * lda + scol;
    bool bv[4];
    const __hip_bfloat16* gB[4];
#pragma unroll
    for (int i = 0; i < 4; ++i) {
        const int br = col0 + i * 32 + srow;
        bv[i] = br < N;
        gB[i] = Bw + (size_t)br * ldb + scol;
    }

    for (int k0 = 0; k0 < Kd; k0 += 64) {
        __syncthreads();
#pragma unroll
        for (int i = 0; i < 4; ++i)
            __builtin_amdgcn_global_load_lds((const AS1 void*)(gA + (size_t)i * 32 * lda + k0),
                (AS3 void*)(Asl + i * 2048 + tid * 8), 16, 0, 0);
#pragma unroll
        for (int i = 0; i < 4; ++i)
            if (bv[i]) __builtin_amdgcn_global_load_lds((const AS1 void*)(gB[i] + k0),
                (AS3 void*)(Bsl + i * 2048 + tid * 8), 16, 0, 0);
        __syncthreads();

#pragma unroll
        for (int ks = 0; ks < 2; ++ks) {
            bf16x8 af[4], bfr[4];
#pragma unroll
            for (int i = 0; i < 4; ++i)
                af[i] = *(const bf16x8*)(Asl + (wm * 64 + i * 16 + lr) * 64 + ks * 32 + lk);
#pragma unroll
            for (int j = 0; j < 4; ++j)
                bfr[j] = *(const bf16x8*)(Bsl + (wn * 64 + j * 16 + lr) * 64 + ks * 32 + lk);
#pragma unroll
            for (int i = 0; i < 4; ++i)
#pragma unroll
                for (int j = 0; j < 4; ++j)
                    acc[i][j] = __builtin_amdgcn_mfma_f32_16x16x32_bf16(
                        af[i], bfr[j], acc[i][j], 0, 0, 0);
        }
    }

    const int orow = (lane >> 4) << 2;
#pragma unroll
    for (int i = 0; i < 4; ++i) {
#pragma unroll
        for (int j = 0; j < 4; ++j) {
            const int col = col0 + wn * 64 + j * 16 + lr;
            if (col >= N) continue;
            const float bvv = bias ? bias[col] : 0.f;
            const int rowb = row0 + wm * 64 + i * 16 + orow;
#pragma unroll
            for (int r = 0; r < 4; ++r)
                C[(size_t)(rowb + r) * ldc + col] = (OutT)(acc[i][j][r] + bvv);
        }
    }
}

// ---------------------------------------------------------------------------
// 64x64-tile bf16 MFMA GEMM body (NT), BK=64, double-buffered LDS with
// T3-minimum 2-phase prefetch: issue next tile's global_load_lds BEFORE the
// current tile's MFMAs, so the (compiler-emitted) vmcnt(0) drain at the
// barrier lands after compute. Cin add for gigh.
// ---------------------------------------------------------------------------
template <typename OutT>
__device__ __forceinline__ void gemm_nt_body(
    const __hip_bfloat16* __restrict__ A, const __hip_bfloat16* __restrict__ Bw,
    const float* __restrict__ bias, const float* __restrict__ Cin, int ldcin,
    OutT* __restrict__ C, int M, int N, int Kd, int lda, int ldb, int ldc,
    int bx, int by)
{
    __shared__ __hip_bfloat16 Asl[2][64 * 64];
    __shared__ __hip_bfloat16 Bsl[2][64 * 64];
    const int tid  = threadIdx.x;
    const int lane = tid & 63;
    const int w    = tid >> 6;
    const int wm   = w >> 1, wn = w & 1;
    const int row0 = by * 64;
    const int col0 = bx * 64;

    const int srow = tid >> 3;           // 0..31 (+32 on 2nd issue)
    const int scol = (tid & 7) << 3;     // 0..56

    const int lr = lane & 15;
    const int lk = (lane >> 4) << 3;

    f32x4 acc[2][2] = {};

    const __hip_bfloat16* gA0 = A + (size_t)(row0 + srow) * lda + scol;
    const __hip_bfloat16* gA1 = gA0 + (size_t)32 * lda;
    const int br0 = col0 + srow, br1 = br0 + 32;
    const __hip_bfloat16* gB0 = Bw + (size_t)br0 * ldb + scol;
    const __hip_bfloat16* gB1 = gB0 + (size_t)32 * ldb;
    const bool v0 = br0 < N, v1 = br1 < N;

    auto stage = [&](int buf, int k0) {
        __builtin_amdgcn_global_load_lds((const AS1 void*)(gA0 + k0),
            (AS3 void*)(&Asl[buf][tid * 8]), 16, 0, 0);
        __builtin_amdgcn_global_load_lds((const AS1 void*)(gA1 + k0),
            (AS3 void*)(&Asl[buf][2048 + tid * 8]), 16, 0, 0);
        if (v0) __builtin_amdgcn_global_load_lds((const AS1 void*)(gB0 + k0),
            (AS3 void*)(&Bsl[buf][tid * 8]), 16, 0, 0);
        if (v1) __builtin_amdgcn_global_load_lds((const AS1 void*)(gB1 + k0),
            (AS3 void*)(&Bsl[buf][2048 + tid * 8]), 16, 0, 0);
    };

    stage(0, 0);
    __syncthreads();            // buf0 ready
    int cur = 0;
    for (int k0 = 0; k0 < Kd; k0 += 64) {
        if (k0 + 64 < Kd) stage(cur ^ 1, k0 + 64);   // prefetch next tile

#pragma unroll
        for (int ks = 0; ks < 2; ++ks) {
            bf16x8 af[2], bfr[2];
#pragma unroll
            for (int i = 0; i < 2; ++i)
                af[i] = *(const bf16x8*)(&Asl[cur][(wm * 32 + i * 16 + lr) * 64 + ks * 32 + lk]);
#pragma unroll
            for (int j = 0; j < 2; ++j)
                bfr[j] = *(const bf16x8*)(&Bsl[cur][(wn * 32 + j * 16 + lr) * 64 + ks * 32 + lk]);
#pragma unroll
            for (int i = 0; i < 2; ++i)
#pragma unroll
                for (int j = 0; j < 2; ++j)
                    acc[i][j] = __builtin_amdgcn_mfma_f32_16x16x32_bf16(
                        af[i], bfr[j], acc[i][j], 0, 0, 0);
        }
        __syncthreads();        // drains prefetch (vmcnt) + reads; next buf ready
        cur ^= 1;
    }

    const int orow = (lane >> 4) << 2;
#pragma unroll
    for (int i = 0; i < 2; ++i) {
#pragma unroll
        for (int j = 0; j < 2; ++j) {
            const int col = col0 + wn * 32 + j * 16 + lr;
            if (col >= N) continue;
            const float bvv = bias ? bias[col] : 0.f;
            const int rowb = row0 + wm * 32 + i * 16 + orow;
#pragma unroll
            for (int r = 0; r < 4; ++r) {
                float v = acc[i][j][r] + bvv;
                if (Cin) v += Cin[(size_t)(rowb + r) * ldcin + col];
                C[(size_t)(rowb + r) * ldc + col] = (OutT)v;
            }
        }
    }
}

// ---------------------------------------------------------------------------
// Fused gi+gh: z==0: gi = ctx @ Wfused^T + gi_emb_t ; z==1: gh = hb @ Whh^T + bhh
// grid (24, 4, 2)
// ---------------------------------------------------------------------------
__global__ __launch_bounds__(256) void gemm_gigh_kernel(
    const __hip_bfloat16* __restrict__ ctx, const __hip_bfloat16* __restrict__ Wf,
    const float* __restrict__ gi_emb_t,
    const __hip_bfloat16* __restrict__ hb, const __hip_bfloat16* __restrict__ Whh,
    const float* __restrict__ bhh,
    float* __restrict__ gi, float* __restrict__ gh)
{
    if (blockIdx.z == 0)
        gemm_nt_body<float>(ctx, Wf, nullptr, gi_emb_t, 3 * H_, gi,
                            B_, 3 * H_, K_, K_, K_, 3 * H_, blockIdx.x, blockIdx.y);
    else
        gemm_nt_body<float>(hb, Whh, bhh, nullptr, 0, gh,
                            B_, 3 * H_, H_, H_, H_, 3 * H_, blockIdx.x, blockIdx.y);
}

// ---------------------------------------------------------------------------
// Fused [GRU(t-1)] + q-projection + additive attention. One block per b,
// 512 threads (8 waves -> 2 waves/SIMD for latency hiding).
// ---------------------------------------------------------------------------
__global__ __launch_bounds__(512) void attn_gru_kernel(
    const float* __restrict__ gi, const float* __restrict__ gh,
    float* __restrict__ h, __hip_bfloat16* __restrict__ hb,
    __hip_bfloat16* __restrict__ h_all, int tprev,
    const __hip_bfloat16* __restrict__ WqT, const float* __restrict__ bq,
    const __hip_bfloat16* __restrict__ kp, const __hip_bfloat16* __restrict__ feat,
    const float* __restrict__ Va, const float* __restrict__ bva,
    __hip_bfloat16* __restrict__ ctx)
{
    const int b = blockIdx.x;
    const int tid = threadIdx.x;       // 0..511
    const int lane = tid & 63;
    const int wave = tid >> 6;         // 0..7
    __shared__ float hb_s[H_];
    __shared__ float q_part[8][H_];    // 16 KB
    __shared__ float q_s[H_];
    __shared__ float s_sc[64];
    __shared__ float s_w[64];

    // ---- GRU(t-1): j = tid covers all H ----
    if (tprev >= 0) {
        const int j = tid;
        const size_t o = (size_t)b * (3 * H_) + j;
        const float ir = gi[o],           hr = gh[o];
        const float iz = gi[o + H_],      hz = gh[o + H_];
        const float in_ = gi[o + 2 * H_], hn = gh[o + 2 * H_];
        const float rr = 1.f / (1.f + expf(-(ir + hr)));
        const float zz = 1.f / (1.f + expf(-(iz + hz)));
        const float nn = tanhf(in_ + rr * hn);
        const size_t hi = (size_t)b * H_ + j;
        const float hnew = (1.f - zz) * nn + zz * h[hi];
        h[hi] = hnew;
        hb_s[j] = hnew;
        const __hip_bfloat16 hv = (__hip_bfloat16)hnew;
        hb[hi] = hv;
        h_all[((size_t)b * T_ + tprev) * H_ + j] = hv;
    } else {
        hb_s[tid] = 0.f;
    }
    __syncthreads();

    // ---- q = h @ Wq^T + bq : 8-wave split-K, lane owns 8 cols ----
    {
        const int j0 = lane * 8;
        float accq[8] = {};
        const __hip_bfloat16* wbase = WqT + (size_t)(wave * 64) * H_ + j0;
#pragma unroll 16
        for (int k = 0; k < 64; ++k) {
            const float hv = hb_s[wave * 64 + k];
            const bf16x8 wv = *(const bf16x8*)(wbase + (size_t)k * H_);
#pragma unroll
            for (int i = 0; i < 8; ++i) accq[i] = fmaf(hv, (float)wv[i], accq[i]);
        }
#pragma unroll
        for (int i = 0; i < 8; ++i) q_part[wave][j0 + i] = accq[i];
    }
    __syncthreads();
    {
        const int j = tid;
        float s = bq[j];
#pragma unroll
        for (int w2 = 0; w2 < 8; ++w2) s += q_part[w2][j];
        q_s[j] = s;
    }
    __syncthreads();

    // ---- scores + softmax ----
    float qr[8], va[8];
#pragma unroll
    for (int i = 0; i < 8; ++i) {
        qr[i] = q_s[lane * 8 + i];
        va[i] = Va[lane * 8 + i];
    }

    for (int l = wave; l < L_; l += 8) {
        const bf16x8 kv = *(const bf16x8*)(kp + ((size_t)b * L_ + l) * H_ + lane * 8);
        float s = 0.f;
#pragma unroll
        for (int i = 0; i < 8; ++i) s += tanh_fast(qr[i] + (float)kv[i]) * va[i];
#pragma unroll
        for (int off = 32; off > 0; off >>= 1) s += __shfl_xor(s, off, 64);
        if (lane == 0) s_sc[l] = s + bva[0];
    }
    __syncthreads();

    if (wave == 0) {
        const float v = (lane < L_) ? s_sc[lane] : -1e30f;
        float m = v;
#pragma unroll
        for (int off = 32; off > 0; off >>= 1) m = fmaxf(m, __shfl_xor(m, off, 64));
        const float e = (lane < L_) ? expf(v - m) : 0.f;
        float ssum = e;
#pragma unroll
        for (int off = 32; off > 0; off >>= 1) ssum += __shfl_xor(ssum, off, 64);
        if (lane < L_) s_w[lane] = e / ssum;
    }
    __syncthreads();

    // ---- ctx: one k per thread ----
    {
        float acc0 = 0.f;
        const __hip_bfloat16* fb = feat + (size_t)b * L_ * K_ + tid;
#pragma unroll 7
        for (int l = 0; l < L_; ++l)
            acc0 = fmaf(s_w[l], (float)fb[(size_t)l * K_], acc0);
        ctx[(size_t)b * K_ + tid] = (__hip_bfloat16)acc0;
    }
}

// ---------------------------------------------------------------------------
// Standalone GRU (final step only).
// ---------------------------------------------------------------------------
__global__ __launch_bounds__(256) void gru_kernel(
    const float* __restrict__ gi, const float* __restrict__ gh,
    float* __restrict__ h, __hip_bfloat16* __restrict__ hb,
    __hip_bfloat16* __restrict__ h_all, int t)
{
    const int idx = blockIdx.x * 256 + threadIdx.x;
    const int b = idx >> 9;
    const int j = idx & (H_ - 1);
    const size_t o = (size_t)b * 3 * H_ + j;
    const float ir = gi[o],           hr = gh[o];
    const float iz = gi[o + H_],      hz = gh[o + H_];
    const float in_ = gi[o + 2 * H_], hn = gh[o + 2 * H_];
    const float r = 1.f / (1.f + expf(-(ir + hr)));
    const float z = 1.f / (1.f + expf(-(iz + hz)));
    const float n = tanhf(in_ + r * hn);
    const float hnew = (1.f - z) * n + z * h[idx];
    h[idx] = hnew;
    const __hip_bfloat16 hv = (__hip_bfloat16)hnew;
    hb[idx] = hv;
    h_all[((size_t)b * T_ + t) * H_ + j] = hv;
}

// ---------------------------------------------------------------------------
extern "C" void kernel_launch(void* const* d_in, const int* in_sizes, int n_in,
                              void* d_out, int out_size, void* d_ws, size_t ws_size,
                              hipStream_t stream)
{
    const float* features = (const float*)d_in[0];
    const int*   captions = (const int*)d_in[1];
    const float* emb  = (const float*)d_in[2];
    const float* Wq   = (const float*)d_in[3];
    const float* bq   = (const float*)d_in[4];
    const float* Uk   = (const float*)d_in[5];
    const float* bk   = (const float*)d_in[6];
    const float* Va   = (const float*)d_in[7];
    const float* bva  = (const float*)d_in[8];
    const float* W0   = (const float*)d_in[9];
    const float* b0   = (const float*)d_in[10];
    const float* Wih  = (const float*)d_in[11];
    const float* bih  = (const float*)d_in[12];
    const float* Whh  = (const float*)d_in[13];
    const float* bhh  = (const float*)d_in[14];
    const float* W1   = (const float*)d_in[15];
    const float* b1   = (const float*)d_in[16];
    float* out = (float*)d_out;

    // fp32 scratch
    float* ws = (float*)d_ws;
    float* h      = ws; ws += B_ * H_;
    float* gi     = ws; ws += B_ * 3 * H_;
    float* gh     = ws; ws += B_ * 3 * H_;
    float* bfull  = ws; ws += 3 * H_;
    float* gi_emb = ws; ws += (size_t)T_ * B_ * 3 * H_;
    // bf16 scratch
    __hip_bfloat16* bws = (__hip_bfloat16*)ws;
    __hip_bfloat16* feat_bf = bws; bws += (size_t)B_ * L_ * K_;
    __hip_bfloat16* kp_bf   = bws; bws += (size_t)B_ * L_ * H_;
    __hip_bfloat16* W1_bf   = bws; bws += (size_t)V_ * H_;
    __hip_bfloat16* Uk_bf   = bws; bws += (size_t)H_ * K_;
    __hip_bfloat16* WqT_bf  = bws; bws += (size_t)H_ * H_;
    __hip_bfloat16* W0T_bf  = bws; bws += (size_t)K_ * H_;
    __hip_bfloat16* Wih_bf  = bws; bws += (size_t)3 * H_ * (E_ + H_);
    __hip_bfloat16* Whh_bf  = bws; bws += (size_t)3 * H_ * H_;
    __hip_bfloat16* Wfused  = bws; bws += (size_t)3 * H_ * K_;
    __hip_bfloat16* emb_all = bws; bws += (size_t)T_ * B_ * E_;
    __hip_bfloat16* hb      = bws; bws += (size_t)B_ * H_;
    __hip_bfloat16* ctx_bf  = bws; bws += (size_t)B_ * K_;
    __hip_bfloat16* h_all   = bws; bws += (size_t)B_ * T_ * H_;

    hipMemsetAsync(h, 0, (size_t)B_ * H_ * sizeof(float), stream);
    hipMemsetAsync(hb, 0, (size_t)B_ * H_ * sizeof(__hip_bfloat16), stream);

    const dim3 blk(256);

    // ---- prologue: merged casts (5 segments, all n4 % 256 == 0) ----
    {
        CvtSegs s;
        s.src[0] = features; s.dst[0] = feat_bf;
        s.src[1] = W1;       s.dst[1] = W1_bf;
        s.src[2] = Uk;       s.dst[2] = Uk_bf;
        s.src[3] = Wih;      s.dst[3] = Wih_bf;
        s.src[4] = Whh;      s.dst[4] = Whh_bf;
        const int nb[5] = {
            B_ * L_ * K_ / 1024, V_ * H_ / 1024, H_ * K_ / 1024,
            3 * H_ * (E_ + H_) / 1024, 3 * H_ * H_ / 1024 };
        int cum = 0;
        for (int i = 0; i < 5; ++i) { cum += nb[i]; s.blk_end[i] = cum; }
        cvt_multi_kernel<<<dim3(cum), blk, 0, stream>>>(s);
    }
    transpose_cast_kernel<<<dim3(H_ / 32, H_ / 32), blk, 0, stream>>>(Wq, WqT_bf, H_, H_);
    transpose_cast_kernel<<<dim3(K_ / 32, H_ / 32), blk, 0, stream>>>(W0, W0T_bf, H_, K_);
    bfull_kernel<<<dim3((3 * H_ + 255) / 256), blk, 0, stream>>>(Wih, b0, bih, bfull);
    emb_gather_kernel<<<dim3(T_ * B_), dim3(128), 0, stream>>>(captions, emb, emb_all);

    // keys_proj = features @ Uk^T + bk -> bf16 [B*L, H]
    gemm_bf16_nt128_kernel<__hip_bfloat16><<<dim3((B_ * L_ / 128) * (H_ / 128)), blk, 0, stream>>>(
        feat_bf, Uk_bf, bk, kp_bf, H_, K_, K_, K_, H_, B_ * L_ / 128);

    // Wfused[3H, K] = Wih[:, E:] @ W0
    gemm_bf16_nt128_kernel<__hip_bfloat16><<<dim3((3 * H_ / 128) * (K_ / 128)), blk, 0, stream>>>(
        Wih_bf + E_, W0T_bf, nullptr, Wfused, K_, H_, E_ + H_, H_, K_, 3 * H_ / 128);

    // gi_emb[t*B+b, :] = emb_t @ WihE^T + (bih + WihE@b0)
    gemm_bf16_nt128_kernel<float><<<dim3((T_ * B_ / 128) * (3 * H_ / 128)), blk, 0, stream>>>(
        emb_all, Wih_bf, bfull, gi_emb, 3 * H_, E_, E_, E_ + H_, 3 * H_, T_ * B_ / 128);

    // ---- recurrence: 2 dispatches per step ----
    for (int t = 0; t < T_; ++t) {
        attn_gru_kernel<<<dim3(B_), dim3(512), 0, stream>>>(
            gi, gh, h, hb, h_all, t - 1,
            WqT_bf, bq, kp_bf, feat_bf, Va, bva, ctx_bf);
        gemm_gigh_kernel<<<dim3(3 * H_ / 64, B_ / 64, 2), blk, 0, stream>>>(
            ctx_bf, Wfused, gi_emb + (size_t)t * B_ * 3 * H_,
            hb, Whh_bf, bhh, gi, gh);
    }
    // final GRU (t = T-1)
    gru_kernel<<<dim3(B_ * H_ / 256), blk, 0, stream>>>(gi, gh, h, hb, h_all, T_ - 1);

    // ---- epilogue: out[b*T+t, :] = h_all @ W1^T + b1 ----
    gemm_bf16_nt128_kernel<float><<<dim3((B_ * T_ / 128) * ((V_ + 127) / 128)), blk, 0, stream>>>(
        h_all, W1_bf, b1, out, V_, H_, H_, H_, V_, B_ * T_ / 128);
}